// Round 5
// baseline (411.669 us; speedup 1.0000x reference)
//
#include <hip/hip_runtime.h>
#include <math.h>
#include <stdint.h>

// Problem dims (fixed)
#define BATCH 4
#define CQ 256      // x channels
#define P 4096      // query positions (64*64)
#define CC 512      // context channels
#define PC 1024     // kv positions (32*32)
#define HID 512     // HEADS*DIM_HEAD
#define HEADS 8
#define DH 64

// Fold attention scale 1/sqrt(64) * log2(e) into Q so softmax uses exp2.
#define QSCALE 0.180336880111113703f

typedef __attribute__((ext_vector_type(8))) __fp16 f16x8;
typedef __attribute__((ext_vector_type(2))) __fp16 f16x2;
typedef __attribute__((ext_vector_type(4))) float f32x4;
typedef __attribute__((ext_vector_type(4))) unsigned int u32x4;

union H2U { f16x2 h; uint32_t u; };
union F8U { uint32_t u[4]; f16x8 v; };

__device__ __forceinline__ uint32_t pkh(float a, float b) {
    H2U z; z.h = __builtin_amdgcn_cvt_pkrtz(a, b); return z.u;
}
__device__ __forceinline__ f16x2 upk(uint32_t w) { H2U z; z.u = w; return z.h; }
__device__ __forceinline__ void split2(float a, float b, uint32_t& hw, uint32_t& lw) {
    hw = pkh(a, b);
    f16x2 h = upk(hw);
    lw = pkh(a - (float)h[0], b - (float)h[1]);
}

#define MFMA16(a, b, c) __builtin_amdgcn_mfma_f32_16x16x32_f16(a, b, c, 0, 0, 0)

// ---------------------------------------------------------------------------
// fp32 tiled GEMM for Q: C = Wq (MxK) * x[b] (KxN); epilogue writes split
// fp16 hi/lo to [b][h][pos][c64], scaled by QSCALE.
// ---------------------------------------------------------------------------
__global__ __launch_bounds__(256) void gemm_q(
    const float* __restrict__ A, const float* __restrict__ B,
    unsigned short* __restrict__ Dh, unsigned short* __restrict__ Dl)
{
    const int b = blockIdx.z;
    const int K = CQ, N = P;
    const float* Bb = B + (size_t)b * K * N;
    const int tn = blockIdx.x * 64;
    const int tm = blockIdx.y * 64;
    const int tid = threadIdx.x;
    const int tx = tid & 15, ty = tid >> 4;

    __shared__ float As[16][68];
    __shared__ float Bs[16][68];

    float acc[4][4] = {};

    for (int k0 = 0; k0 < K; k0 += 16) {
        {
            int m = tid >> 2;
            int kk = (tid & 3) * 4;
            const float4 a4 = *reinterpret_cast<const float4*>(
                &A[(size_t)(tm + m) * K + k0 + kk]);
            As[kk + 0][m] = a4.x; As[kk + 1][m] = a4.y;
            As[kk + 2][m] = a4.z; As[kk + 3][m] = a4.w;
        }
        {
            int kk = tid >> 4;
            int n = (tid & 15) * 4;
            *reinterpret_cast<float4*>(&Bs[kk][n]) =
                *reinterpret_cast<const float4*>(&Bb[(size_t)(k0 + kk) * N + tn + n]);
        }
        __syncthreads();
        #pragma unroll
        for (int kk = 0; kk < 16; ++kk) {
            float4 a = *reinterpret_cast<const float4*>(&As[kk][ty * 4]);
            float4 bv = *reinterpret_cast<const float4*>(&Bs[kk][tx * 4]);
            float av[4] = {a.x, a.y, a.z, a.w};
            float bb[4] = {bv.x, bv.y, bv.z, bv.w};
            #pragma unroll
            for (int i2 = 0; i2 < 4; ++i2)
                #pragma unroll
                for (int j2 = 0; j2 < 4; ++j2)
                    acc[i2][j2] = fmaf(av[i2], bb[j2], acc[i2][j2]);
        }
        __syncthreads();
    }

    const int h = tm >> 6;
    #pragma unroll
    for (int j2 = 0; j2 < 4; ++j2) {
        int pos = tn + tx * 4 + j2;
        uint32_t hw0, hw1, lw0, lw1;
        split2(QSCALE * acc[0][j2], QSCALE * acc[1][j2], hw0, lw0);
        split2(QSCALE * acc[2][j2], QSCALE * acc[3][j2], hw1, lw1);
        size_t off = (((size_t)b * HEADS + h) * (size_t)N + pos) * 64 + ty * 4;
        uint2 hh; hh.x = hw0; hh.y = hw1;
        uint2 ll; ll.x = lw0; ll.y = lw1;
        *reinterpret_cast<uint2*>(Dh + off) = hh;
        *reinterpret_cast<uint2*>(Dl + off) = ll;
    }
}

// ---------------------------------------------------------------------------
// Fused K+V projection: blockIdx.y selects weight/output. K -> [b][h][pos][64]
// (pos-major), V -> [b][c][pos] (channel-major). fp16 hi/lo epilogues.
// ---------------------------------------------------------------------------
__global__ __launch_bounds__(256) void gemm_kv(
    const float* __restrict__ Wk, const float* __restrict__ Wv,
    const float* __restrict__ B,
    unsigned short* __restrict__ Kh, unsigned short* __restrict__ Kl,
    unsigned short* __restrict__ Vh, unsigned short* __restrict__ Vl)
{
    const int b = blockIdx.z;
    const int K = CC, N = PC;
    const int sel = blockIdx.y >> 3;           // 0: K-proj, 1: V-proj
    const float* A = sel ? Wv : Wk;
    const float* Bb = B + (size_t)b * K * N;
    const int tn = blockIdx.x * 64;
    const int tm = (blockIdx.y & 7) * 64;
    const int tid = threadIdx.x;
    const int tx = tid & 15, ty = tid >> 4;

    __shared__ float As[16][68];
    __shared__ float Bs[16][68];

    float acc[4][4] = {};

    for (int k0 = 0; k0 < K; k0 += 16) {
        {
            int m = tid >> 2;
            int kk = (tid & 3) * 4;
            const float4 a4 = *reinterpret_cast<const float4*>(
                &A[(size_t)(tm + m) * K + k0 + kk]);
            As[kk + 0][m] = a4.x; As[kk + 1][m] = a4.y;
            As[kk + 2][m] = a4.z; As[kk + 3][m] = a4.w;
        }
        {
            int kk = tid >> 4;
            int n = (tid & 15) * 4;
            *reinterpret_cast<float4*>(&Bs[kk][n]) =
                *reinterpret_cast<const float4*>(&Bb[(size_t)(k0 + kk) * N + tn + n]);
        }
        __syncthreads();
        #pragma unroll
        for (int kk = 0; kk < 16; ++kk) {
            float4 a = *reinterpret_cast<const float4*>(&As[kk][ty * 4]);
            float4 bv = *reinterpret_cast<const float4*>(&Bs[kk][tx * 4]);
            float av[4] = {a.x, a.y, a.z, a.w};
            float bb[4] = {bv.x, bv.y, bv.z, bv.w};
            #pragma unroll
            for (int i2 = 0; i2 < 4; ++i2)
                #pragma unroll
                for (int j2 = 0; j2 < 4; ++j2)
                    acc[i2][j2] = fmaf(av[i2], bb[j2], acc[i2][j2]);
        }
        __syncthreads();
    }

    if (sel == 0) {
        const int h = tm >> 6;
        #pragma unroll
        for (int j2 = 0; j2 < 4; ++j2) {
            int pos = tn + tx * 4 + j2;
            uint32_t hw0, hw1, lw0, lw1;
            split2(acc[0][j2], acc[1][j2], hw0, lw0);
            split2(acc[2][j2], acc[3][j2], hw1, lw1);
            size_t off = (((size_t)b * HEADS + h) * (size_t)N + pos) * 64 + ty * 4;
            uint2 hh; hh.x = hw0; hh.y = hw1;
            uint2 ll; ll.x = lw0; ll.y = lw1;
            *reinterpret_cast<uint2*>(Kh + off) = hh;
            *reinterpret_cast<uint2*>(Kl + off) = ll;
        }
    } else {
        #pragma unroll
        for (int i2 = 0; i2 < 4; ++i2) {
            int c = tm + ty * 4 + i2;
            uint32_t hw0, hw1, lw0, lw1;
            split2(acc[i2][0], acc[i2][1], hw0, lw0);
            split2(acc[i2][2], acc[i2][3], hw1, lw1);
            size_t off = ((size_t)b * HID + c) * (size_t)N + tn + tx * 4;
            uint2 hh; hh.x = hw0; hh.y = hw1;
            uint2 ll; ll.x = lw0; ll.y = lw1;
            *reinterpret_cast<uint2*>(Vh + off) = hh;
            *reinterpret_cast<uint2*>(Vl + off) = ll;
        }
    }
}

// ---------------------------------------------------------------------------
// Split Wo into fp16 hi only (2-term output projection).
// ---------------------------------------------------------------------------
__global__ __launch_bounds__(256) void split_w(
    const float* __restrict__ W, unsigned short* __restrict__ Wh, int n)
{
    int i = blockIdx.x * 256 + threadIdx.x;
    if (i < n) Wh[i] = (unsigned short)(pkh(W[i], 0.f) & 0xffffu);
}

// ---------------------------------------------------------------------------
// Flash attention, split-fp16 MFMA. Wave = 32 queries (4096 waves total ->
// 4 waves/SIMD). grid.x = (h,b) composite so K/V-panel sharers co-locate on
// one XCD. V issued before S-MFMAs; defer-max skips rescale (THR=1).
// S = 3-term split, PV = 2-term (P hi).
// ---------------------------------------------------------------------------
#define NIN 2
__global__ __launch_bounds__(256, 4) void attn_mfma(
    const unsigned short* __restrict__ qh, const unsigned short* __restrict__ ql,
    const unsigned short* __restrict__ kh, const unsigned short* __restrict__ kl,
    const unsigned short* __restrict__ vh, const unsigned short* __restrict__ vl,
    uint32_t* __restrict__ ohl)
{
    const int wid = threadIdx.x >> 6;
    const int l = threadIdx.x & 63;
    const int ln = l & 15, g = l >> 4;
    const int hb = blockIdx.x;                 // (h, b) composite
    const int h = hb & 7, b = hb >> 3;
    const int i0 = (blockIdx.y * 4 + wid) * 32;

    const size_t qbase = (size_t)(b * HEADS + h) * P * 64;
    const size_t kbase = (size_t)(b * HEADS + h) * PC * 64;
    const size_t vbase = (size_t)(b * HID + h * DH) * PC;

    // Q B-frags: lane holds q[i=i0+16in+ln][c=32ks+8g .. +7], hi/lo
    f16x8 qf[NIN][2][2];
    #pragma unroll
    for (int in_ = 0; in_ < NIN; ++in_) {
        const size_t qrow = qbase + (size_t)(i0 + 16 * in_ + ln) * 64 + 8 * g;
        #pragma unroll
        for (int ks = 0; ks < 2; ++ks) {
            qf[in_][ks][0] = *reinterpret_cast<const f16x8*>(qh + qrow + 32 * ks);
            qf[in_][ks][1] = *reinterpret_cast<const f16x8*>(ql + qrow + 32 * ks);
        }
    }

    f32x4 acc[4][NIN];  // O^T frags: rows c=16cm+4g+r, col i=16in+ln
    #pragma unroll
    for (int cm = 0; cm < 4; ++cm)
        #pragma unroll
        for (int in_ = 0; in_ < NIN; ++in_) {
            f32x4 z = {0.f, 0.f, 0.f, 0.f};
            acc[cm][in_] = z;
        }
    float mst[NIN], lst[NIN];
    #pragma unroll
    for (int in_ = 0; in_ < NIN; ++in_) { mst[in_] = -1e30f; lst[in_] = 0.f; }

    const int idx0 = ln + 16 * (2 * (g & 1));
    const int idx1 = idx0 + 16;
    const bool topTile = (g & 2) != 0;

    for (int jt = 0; jt < 32; ++jt) {
        const int j0 = jt * 32;

        // ---- K frags for this step ----
        f16x8 kf[2][2][2];
        #pragma unroll
        for (int jm = 0; jm < 2; ++jm) {
            const size_t krow = kbase + (size_t)(j0 + 16 * jm + ln) * 64 + 8 * g;
            #pragma unroll
            for (int ks = 0; ks < 2; ++ks) {
                kf[jm][ks][0] = *reinterpret_cast<const f16x8*>(kh + krow + 32 * ks);
                kf[jm][ks][1] = *reinterpret_cast<const f16x8*>(kl + krow + 32 * ks);
            }
        }
        // ---- V frags issued early (consumed after softmax) ----
        f16x8 vfh[4], vfl[4];
        #pragma unroll
        for (int cm = 0; cm < 4; ++cm) {
            const size_t vrow = vbase + (size_t)(16 * cm + ln) * PC + j0 + 8 * g;
            vfh[cm] = *reinterpret_cast<const f16x8*>(vh + vrow);
            vfl[cm] = *reinterpret_cast<const f16x8*>(vl + vrow);
        }

        // ---- S^T = K * Q (3-term split) ----
        f32x4 s[2][NIN];
        #pragma unroll
        for (int jm = 0; jm < 2; ++jm)
            #pragma unroll
            for (int in_ = 0; in_ < NIN; ++in_) {
                f32x4 z = {0.f, 0.f, 0.f, 0.f};
                s[jm][in_] = z;
            }
        #pragma unroll
        for (int jm = 0; jm < 2; ++jm)
            #pragma unroll
            for (int ks = 0; ks < 2; ++ks)
                #pragma unroll
                for (int in_ = 0; in_ < NIN; ++in_) {
                    s[jm][in_] = MFMA16(kf[jm][ks][0], qf[in_][ks][0], s[jm][in_]);
                    s[jm][in_] = MFMA16(kf[jm][ks][0], qf[in_][ks][1], s[jm][in_]);
                    s[jm][in_] = MFMA16(kf[jm][ks][1], qf[in_][ks][0], s[jm][in_]);
                }

        // ---- online softmax with defer-max ----
        uint32_t pw[2][NIN][2];
        #pragma unroll
        for (int in_ = 0; in_ < NIN; ++in_) {
            float tmx = fmaxf(fmaxf(fmaxf(s[0][in_][0], s[0][in_][1]),
                                    fmaxf(s[0][in_][2], s[0][in_][3])),
                              fmaxf(fmaxf(s[1][in_][0], s[1][in_][1]),
                                    fmaxf(s[1][in_][2], s[1][in_][3])));
            tmx = fmaxf(tmx, __shfl_xor(tmx, 16, 64));
            tmx = fmaxf(tmx, __shfl_xor(tmx, 32, 64));
            const bool skip = __all(tmx <= mst[in_] + 1.0f);
            float mnew = skip ? mst[in_] : fmaxf(mst[in_], tmx);
            float rs = 0.f;
            #pragma unroll
            for (int jm = 0; jm < 2; ++jm)
                #pragma unroll
                for (int r = 0; r < 4; ++r) {
                    float p = exp2f(s[jm][in_][r] - mnew);
                    s[jm][in_][r] = p; rs += p;
                }
            rs += __shfl_xor(rs, 16, 64);
            rs += __shfl_xor(rs, 32, 64);
            if (skip) {
                lst[in_] += rs;
            } else {
                float fac = exp2f(mst[in_] - mnew);
                lst[in_] = lst[in_] * fac + rs;
                mst[in_] = mnew;
                #pragma unroll
                for (int cm = 0; cm < 4; ++cm) acc[cm][in_] *= fac;
            }
            #pragma unroll
            for (int jm = 0; jm < 2; ++jm) {
                pw[jm][in_][0] = pkh(s[jm][in_][0], s[jm][in_][1]);
                pw[jm][in_][1] = pkh(s[jm][in_][2], s[jm][in_][3]);
            }
        }

        // ---- P redistribution + O^T += V * P (2-term) ----
        #pragma unroll
        for (int in_ = 0; in_ < NIN; ++in_) {
            int w00 = (int)pw[0][in_][0], w01 = (int)pw[0][in_][1];
            int w10 = (int)pw[1][in_][0], w11 = (int)pw[1][in_][1];
            int a0 = __shfl(w00, idx0, 64), a1 = __shfl(w01, idx0, 64);
            int a2 = __shfl(w00, idx1, 64), a3 = __shfl(w01, idx1, 64);
            int b0 = __shfl(w10, idx0, 64), b1 = __shfl(w11, idx0, 64);
            int b2 = __shfl(w10, idx1, 64), b3 = __shfl(w11, idx1, 64);
            F8U fu;
            fu.u[0] = (uint32_t)(topTile ? b0 : a0);
            fu.u[1] = (uint32_t)(topTile ? b1 : a1);
            fu.u[2] = (uint32_t)(topTile ? b2 : a2);
            fu.u[3] = (uint32_t)(topTile ? b3 : a3);
            #pragma unroll
            for (int cm = 0; cm < 4; ++cm) {
                acc[cm][in_] = MFMA16(vfh[cm], fu.v, acc[cm][in_]);
                acc[cm][in_] = MFMA16(vfl[cm], fu.v, acc[cm][in_]);
            }
        }
    }

    // epilogue: O/l -> interleaved fp16 hi/lo [h01,h23,l01,l23]
    #pragma unroll
    for (int in_ = 0; in_ < NIN; ++in_) {
        float inv = 1.0f / lst[in_];
        int i = i0 + 16 * in_ + ln;
        #pragma unroll
        for (int cm = 0; cm < 4; ++cm) {
            f32x4 o4 = acc[cm][in_] * inv;
            uint32_t h01, h23, l01, l23;
            split2(o4[0], o4[1], h01, l01);
            split2(o4[2], o4[3], h23, l23);
            u32x4 wv; wv[0] = h01; wv[1] = h23; wv[2] = l01; wv[3] = l23;
            size_t idx = ((size_t)b * P + i) * 512 + (size_t)(h * DH + 16 * cm + 4 * g);
            *reinterpret_cast<u32x4*>(ohl + idx) = wv;
        }
    }
}

// ---------------------------------------------------------------------------
// Output projection: out[b][o][i] = Wo[o][:] . O[b][i][:] + bo[o].
// 2-term fp16 MFMA. Wave = 32o x 32i -> 4096 waves. grid.x = itile so the
// 8 otile-blocks sharing a B-panel co-locate on one XCD.
// ---------------------------------------------------------------------------
__global__ __launch_bounds__(256, 4) void out_proj(
    const unsigned short* __restrict__ woh, const uint32_t* __restrict__ ohl,
    const float* __restrict__ bo, float* __restrict__ out)
{
    const int wid = threadIdx.x >> 6;
    const int l = threadIdx.x & 63;
    const int ln = l & 15, g = l >> 4;
    const int ibase = blockIdx.x * 128 + wid * 32;
    const int otile = blockIdx.y * 32;
    const int b = blockIdx.z;

    f32x4 acc[2][2];
    #pragma unroll
    for (int mt = 0; mt < 2; ++mt)
        #pragma unroll
        for (int nt = 0; nt < 2; ++nt) {
            f32x4 z = {0.f, 0.f, 0.f, 0.f};
            acc[mt][nt] = z;
        }

    #pragma unroll
    for (int ks = 0; ks < 16; ++ks) {
        const int c0 = 32 * ks + 8 * g;
        f16x8 wf[2];
        #pragma unroll
        for (int mt = 0; mt < 2; ++mt)
            wf[mt] = *reinterpret_cast<const f16x8*>(
                woh + (size_t)(otile + 16 * mt + ln) * HID + c0);
        #pragma unroll
        for (int nt = 0; nt < 2; ++nt) {
            const size_t obase = ((size_t)b * P + ibase + 16 * nt + ln) * 512 + c0;
            u32x4 A = *reinterpret_cast<const u32x4*>(ohl + obase);
            u32x4 Bv = *reinterpret_cast<const u32x4*>(ohl + obase + 4);
            F8U bh, bl;
            bh.u[0] = A[0]; bh.u[1] = A[1]; bh.u[2] = Bv[0]; bh.u[3] = Bv[1];
            bl.u[0] = A[2]; bl.u[1] = A[3]; bl.u[2] = Bv[2]; bl.u[3] = Bv[3];
            #pragma unroll
            for (int mt = 0; mt < 2; ++mt) {
                acc[mt][nt] = MFMA16(wf[mt], bh.v, acc[mt][nt]);
                acc[mt][nt] = MFMA16(wf[mt], bl.v, acc[mt][nt]);
            }
        }
    }

    #pragma unroll
    for (int mt = 0; mt < 2; ++mt)
        #pragma unroll
        for (int r = 0; r < 4; ++r) {
            int o_ = otile + 16 * mt + 4 * g + r;
            float bv = bo[o_];
            #pragma unroll
            for (int nt = 0; nt < 2; ++nt)
                out[((size_t)b * CQ + o_) * P + ibase + 16 * nt + ln] =
                    acc[mt][nt][r] + bv;
        }
}

extern "C" void kernel_launch(void* const* d_in, const int* in_sizes, int n_in,
                              void* d_out, int out_size, void* d_ws, size_t ws_size,
                              hipStream_t stream) {
    (void)in_sizes; (void)n_in; (void)out_size; (void)ws_size;
    const float* x   = (const float*)d_in[0];
    const float* ctx = (const float*)d_in[1];
    const float* Wq  = (const float*)d_in[2];
    const float* Wk  = (const float*)d_in[3];
    const float* Wv  = (const float*)d_in[4];
    const float* Wo  = (const float*)d_in[5];
    const float* bo  = (const float*)d_in[6];
    float* out = (float*)d_out;

    unsigned short* qh = (unsigned short*)d_ws;            // 8388608
    unsigned short* ql = qh + (size_t)8388608;
    unsigned short* kh = ql + (size_t)8388608;             // 2097152
    unsigned short* kl = kh + (size_t)2097152;
    unsigned short* vh = kl + (size_t)2097152;
    unsigned short* vl = vh + (size_t)2097152;
    unsigned short* woh = vl + (size_t)2097152;            // 131072
    uint32_t* ohl = (uint32_t*)(woh + (size_t)2 * 131072); // 8388608 u32, 16B-aligned

    dim3 blk(256);
    split_w<<<dim3(512), blk, 0, stream>>>(Wo, woh, CQ * HID);
    // Q = (QSCALE * Wq) @ x   -> [b][h][4096][64] fp16 hi/lo
    gemm_q<<<dim3(P / 64, HID / 64, BATCH), blk, 0, stream>>>(Wq, x, qh, ql);
    // K,V fused              -> K: [b][h][1024][64], V: [b][512][1024]
    gemm_kv<<<dim3(PC / 64, 16, BATCH), blk, 0, stream>>>(
        Wk, Wv, ctx, kh, kl, vh, vl);
    // attention -> ohl (fp16 hi/lo interleaved) [b][i][512]
    attn_mfma<<<dim3(HEADS * BATCH, P / 128), blk, 0, stream>>>(
        qh, ql, kh, kl, vh, vl, ohl);
    // out = Wo @ O + bo
    out_proj<<<dim3(P / 128, CQ / 32, BATCH), blk, 0, stream>>>(
        woh, ohl, bo, out);
}

// Round 6
// 384.709 us; speedup vs baseline: 1.0701x; 1.0701x over previous
//
#include <hip/hip_runtime.h>
#include <math.h>
#include <stdint.h>

// Problem dims (fixed)
#define BATCH 4
#define CQ 256      // x channels
#define P 4096      // query positions (64*64)
#define CC 512      // context channels
#define PC 1024     // kv positions (32*32)
#define HID 512     // HEADS*DIM_HEAD
#define HEADS 8
#define DH 64

// Fold attention scale 1/sqrt(64) * log2(e) into Q so softmax uses exp2.
#define QSCALE 0.180336880111113703f

typedef __attribute__((ext_vector_type(8))) __fp16 f16x8;
typedef __attribute__((ext_vector_type(2))) __fp16 f16x2;
typedef __attribute__((ext_vector_type(4))) float f32x4;
typedef __attribute__((ext_vector_type(4))) unsigned int u32x4;

union H2U { f16x2 h; uint32_t u; };
union F8U { uint32_t u[4]; f16x8 v; };

__device__ __forceinline__ uint32_t pkh(float a, float b) {
    H2U z; z.h = __builtin_amdgcn_cvt_pkrtz(a, b); return z.u;
}
__device__ __forceinline__ f16x2 upk(uint32_t w) { H2U z; z.u = w; return z.h; }
__device__ __forceinline__ void split2(float a, float b, uint32_t& hw, uint32_t& lw) {
    hw = pkh(a, b);
    f16x2 h = upk(hw);
    lw = pkh(a - (float)h[0], b - (float)h[1]);
}

#define MFMA16(a, b, c) __builtin_amdgcn_mfma_f32_16x16x32_f16(a, b, c, 0, 0, 0)

// async global -> LDS, 16B per lane. lds base must be wave-uniform.
__device__ __forceinline__ void gl_lds16(const unsigned short* g, unsigned short* l) {
    __builtin_amdgcn_global_load_lds(
        (const __attribute__((address_space(1))) unsigned int*)g,
        (__attribute__((address_space(3))) unsigned int*)l, 16, 0, 0);
}

// ---------------------------------------------------------------------------
// fp32 tiled GEMM for Q: C = Wq (MxK) * x[b] (KxN); epilogue writes split
// fp16 hi/lo to [b][h][pos][c64], scaled by QSCALE.
// ---------------------------------------------------------------------------
__global__ __launch_bounds__(256) void gemm_q(
    const float* __restrict__ A, const float* __restrict__ B,
    unsigned short* __restrict__ Dh, unsigned short* __restrict__ Dl)
{
    const int b = blockIdx.z;
    const int K = CQ, N = P;
    const float* Bb = B + (size_t)b * K * N;
    const int tn = blockIdx.x * 64;
    const int tm = blockIdx.y * 64;
    const int tid = threadIdx.x;
    const int tx = tid & 15, ty = tid >> 4;

    __shared__ float As[16][68];
    __shared__ float Bs[16][68];

    float acc[4][4] = {};

    for (int k0 = 0; k0 < K; k0 += 16) {
        {
            int m = tid >> 2;
            int kk = (tid & 3) * 4;
            const float4 a4 = *reinterpret_cast<const float4*>(
                &A[(size_t)(tm + m) * K + k0 + kk]);
            As[kk + 0][m] = a4.x; As[kk + 1][m] = a4.y;
            As[kk + 2][m] = a4.z; As[kk + 3][m] = a4.w;
        }
        {
            int kk = tid >> 4;
            int n = (tid & 15) * 4;
            *reinterpret_cast<float4*>(&Bs[kk][n]) =
                *reinterpret_cast<const float4*>(&Bb[(size_t)(k0 + kk) * N + tn + n]);
        }
        __syncthreads();
        #pragma unroll
        for (int kk = 0; kk < 16; ++kk) {
            float4 a = *reinterpret_cast<const float4*>(&As[kk][ty * 4]);
            float4 bv = *reinterpret_cast<const float4*>(&Bs[kk][tx * 4]);
            float av[4] = {a.x, a.y, a.z, a.w};
            float bb[4] = {bv.x, bv.y, bv.z, bv.w};
            #pragma unroll
            for (int i2 = 0; i2 < 4; ++i2)
                #pragma unroll
                for (int j2 = 0; j2 < 4; ++j2)
                    acc[i2][j2] = fmaf(av[i2], bb[j2], acc[i2][j2]);
        }
        __syncthreads();
    }

    const int h = tm >> 6;
    #pragma unroll
    for (int j2 = 0; j2 < 4; ++j2) {
        int pos = tn + tx * 4 + j2;
        uint32_t hw0, hw1, lw0, lw1;
        split2(QSCALE * acc[0][j2], QSCALE * acc[1][j2], hw0, lw0);
        split2(QSCALE * acc[2][j2], QSCALE * acc[3][j2], hw1, lw1);
        size_t off = (((size_t)b * HEADS + h) * (size_t)N + pos) * 64 + ty * 4;
        uint2 hh; hh.x = hw0; hh.y = hw1;
        uint2 ll; ll.x = lw0; ll.y = lw1;
        *reinterpret_cast<uint2*>(Dh + off) = hh;
        *reinterpret_cast<uint2*>(Dl + off) = ll;
    }
}

// ---------------------------------------------------------------------------
// Fused K+V projection: blockIdx.y selects weight/output. K -> [b][h][pos][64]
// (pos-major), V -> [b][c][pos] (channel-major). fp16 hi/lo epilogues.
// ---------------------------------------------------------------------------
__global__ __launch_bounds__(256) void gemm_kv(
    const float* __restrict__ Wk, const float* __restrict__ Wv,
    const float* __restrict__ B,
    unsigned short* __restrict__ Kh, unsigned short* __restrict__ Kl,
    unsigned short* __restrict__ Vh, unsigned short* __restrict__ Vl)
{
    const int b = blockIdx.z;
    const int K = CC, N = PC;
    const int sel = blockIdx.y >> 3;           // 0: K-proj, 1: V-proj
    const float* A = sel ? Wv : Wk;
    const float* Bb = B + (size_t)b * K * N;
    const int tn = blockIdx.x * 64;
    const int tm = (blockIdx.y & 7) * 64;
    const int tid = threadIdx.x;
    const int tx = tid & 15, ty = tid >> 4;

    __shared__ float As[16][68];
    __shared__ float Bs[16][68];

    float acc[4][4] = {};

    for (int k0 = 0; k0 < K; k0 += 16) {
        {
            int m = tid >> 2;
            int kk = (tid & 3) * 4;
            const float4 a4 = *reinterpret_cast<const float4*>(
                &A[(size_t)(tm + m) * K + k0 + kk]);
            As[kk + 0][m] = a4.x; As[kk + 1][m] = a4.y;
            As[kk + 2][m] = a4.z; As[kk + 3][m] = a4.w;
        }
        {
            int kk = tid >> 4;
            int n = (tid & 15) * 4;
            *reinterpret_cast<float4*>(&Bs[kk][n]) =
                *reinterpret_cast<const float4*>(&Bb[(size_t)(k0 + kk) * N + tn + n]);
        }
        __syncthreads();
        #pragma unroll
        for (int kk = 0; kk < 16; ++kk) {
            float4 a = *reinterpret_cast<const float4*>(&As[kk][ty * 4]);
            float4 bv = *reinterpret_cast<const float4*>(&Bs[kk][tx * 4]);
            float av[4] = {a.x, a.y, a.z, a.w};
            float bb[4] = {bv.x, bv.y, bv.z, bv.w};
            #pragma unroll
            for (int i2 = 0; i2 < 4; ++i2)
                #pragma unroll
                for (int j2 = 0; j2 < 4; ++j2)
                    acc[i2][j2] = fmaf(av[i2], bb[j2], acc[i2][j2]);
        }
        __syncthreads();
    }

    if (sel == 0) {
        const int h = tm >> 6;
        #pragma unroll
        for (int j2 = 0; j2 < 4; ++j2) {
            int pos = tn + tx * 4 + j2;
            uint32_t hw0, hw1, lw0, lw1;
            split2(acc[0][j2], acc[1][j2], hw0, lw0);
            split2(acc[2][j2], acc[3][j2], hw1, lw1);
            size_t off = (((size_t)b * HEADS + h) * (size_t)N + pos) * 64 + ty * 4;
            uint2 hh; hh.x = hw0; hh.y = hw1;
            uint2 ll; ll.x = lw0; ll.y = lw1;
            *reinterpret_cast<uint2*>(Kh + off) = hh;
            *reinterpret_cast<uint2*>(Kl + off) = ll;
        }
    } else {
        #pragma unroll
        for (int i2 = 0; i2 < 4; ++i2) {
            int c = tm + ty * 4 + i2;
            uint32_t hw0, hw1, lw0, lw1;
            split2(acc[i2][0], acc[i2][1], hw0, lw0);
            split2(acc[i2][2], acc[i2][3], hw1, lw1);
            size_t off = ((size_t)b * HID + c) * (size_t)N + tn + tx * 4;
            uint2 hh; hh.x = hw0; hh.y = hw1;
            uint2 ll; ll.x = lw0; ll.y = lw1;
            *reinterpret_cast<uint2*>(Vh + off) = hh;
            *reinterpret_cast<uint2*>(Vl + off) = ll;
        }
    }
}

// ---------------------------------------------------------------------------
// Split Wo into fp16 hi only (2-term output projection).
// ---------------------------------------------------------------------------
__global__ __launch_bounds__(256) void split_w(
    const float* __restrict__ W, unsigned short* __restrict__ Wh, int n)
{
    int i = blockIdx.x * 256 + threadIdx.x;
    if (i < n) Wh[i] = (unsigned short)(pkh(W[i], 0.f) & 0xffffu);
}

// ---------------------------------------------------------------------------
// Flash attention, split-fp16 MFMA + LDS-staged K/V shared by 4 waves.
// Block = 4 waves x 32 queries. Per jt-step the block stages K(hi,lo) 32x64
// and V(hi|lo) 64x(32|32) into a 16KB LDS buffer (double-buffered) via
// global_load_lds, XOR-swizzled (slot ^= row&7) for conflict-free b128 reads.
// S = 3-term split, PV = 2-term (P hi). Defer-max online softmax.
// ---------------------------------------------------------------------------
#define NIN 2
#define JBLK 32
#define NJT (PC / JBLK)

__global__ __launch_bounds__(256, 3) void attn_mfma(
    const unsigned short* __restrict__ qh, const unsigned short* __restrict__ ql,
    const unsigned short* __restrict__ kh, const unsigned short* __restrict__ kl,
    const unsigned short* __restrict__ vh, const unsigned short* __restrict__ vl,
    uint32_t* __restrict__ ohl)
{
    const int wid = threadIdx.x >> 6;
    const int l = threadIdx.x & 63;
    const int ln = l & 15, g = l >> 4;
    const int rx = ln & 7;                     // row&7 for all frag rows
    const int hb = blockIdx.x;                 // (h, b) composite
    const int h = hb & 7, b = hb >> 3;
    const int i0 = (blockIdx.y * 4 + wid) * 32;

    const size_t qbase = (size_t)(b * HEADS + h) * P * 64;
    const size_t kbase = (size_t)(b * HEADS + h) * PC * 64;
    const size_t vbase = (size_t)(b * HID + h * DH) * PC;

    // per buf (8192 hw = 16KB): [0,2048) Kh 32x64 | [2048,4096) Kl | [4096,8192) V 64x(hi32|lo32)
    __shared__ unsigned short smem[2][8192];

    // Q B-frags: lane holds q[i=i0+16in+ln][c=32ks+8g .. +7], hi/lo
    f16x8 qf[NIN][2][2];
    #pragma unroll
    for (int in_ = 0; in_ < NIN; ++in_) {
        const size_t qrow = qbase + (size_t)(i0 + 16 * in_ + ln) * 64 + 8 * g;
        #pragma unroll
        for (int ks = 0; ks < 2; ++ks) {
            qf[in_][ks][0] = *reinterpret_cast<const f16x8*>(qh + qrow + 32 * ks);
            qf[in_][ks][1] = *reinterpret_cast<const f16x8*>(ql + qrow + 32 * ks);
        }
    }

    f32x4 acc[4][NIN];
    #pragma unroll
    for (int cm = 0; cm < 4; ++cm)
        #pragma unroll
        for (int in_ = 0; in_ < NIN; ++in_) {
            f32x4 z = {0.f, 0.f, 0.f, 0.f};
            acc[cm][in_] = z;
        }
    float mst[NIN], lst[NIN];
    #pragma unroll
    for (int in_ = 0; in_ < NIN; ++in_) { mst[in_] = -1e30f; lst[in_] = 0.f; }

    const int idx0 = ln + 16 * (2 * (g & 1));
    const int idx1 = idx0 + 16;
    const bool topTile = (g & 2) != 0;

    // ---- staging: 16 segs of 1KB; wave stages segs wid*4 .. wid*4+3 ----
    auto stage = [&](int buf, int jt) {
        const int j0 = jt * JBLK;
        #pragma unroll
        for (int t = 0; t < 4; ++t) {
            const int s = wid * 4 + t;
            unsigned short* lbase = &smem[buf][s * 512];
            const unsigned short* src;
            if (s < 4) {                       // Kh: chunk i = s*64 + l
                int i = s * 64 + l;
                int row = i >> 3, p = i & 7;
                src = kh + kbase + (size_t)(j0 + row) * 64 + 8 * (p ^ (row & 7));
            } else if (s < 8) {                // Kl
                int i = (s - 4) * 64 + l;
                int row = i >> 3, p = i & 7;
                src = kl + kbase + (size_t)(j0 + row) * 64 + 8 * (p ^ (row & 7));
            } else {                           // V hi|lo interleaved rows
                int i = (s - 8) * 64 + l;
                int row = i >> 3, p = i & 7;
                int slog = p ^ (row & 7);
                src = (slog < 4)
                    ? vh + vbase + (size_t)row * PC + j0 + 8 * slog
                    : vl + vbase + (size_t)row * PC + j0 + 8 * (slog - 4);
            }
            gl_lds16(src, lbase);
        }
    };

    stage(0, 0);
    __syncthreads();

    for (int jt = 0; jt < NJT; ++jt) {
        const int cur = jt & 1;
        if (jt + 1 < NJT) stage(cur ^ 1, jt + 1);
        const unsigned short* sm = &smem[cur][0];

        // ---- K frags from LDS (swizzled) ----
        f16x8 kf[2][2][2];
        #pragma unroll
        for (int jm = 0; jm < 2; ++jm)
            #pragma unroll
            for (int ks = 0; ks < 2; ++ks) {
                const int base = (16 * jm + ln) * 64 + 8 * ((4 * ks + g) ^ rx);
                kf[jm][ks][0] = *reinterpret_cast<const f16x8*>(sm + base);
                kf[jm][ks][1] = *reinterpret_cast<const f16x8*>(sm + 2048 + base);
            }
        // ---- V frags from LDS (swizzled) ----
        f16x8 vfh[4], vfl[4];
        #pragma unroll
        for (int cm = 0; cm < 4; ++cm) {
            const int vrow = 4096 + (16 * cm + ln) * 64;
            vfh[cm] = *reinterpret_cast<const f16x8*>(sm + vrow + 8 * (g ^ rx));
            vfl[cm] = *reinterpret_cast<const f16x8*>(sm + vrow + 8 * ((4 + g) ^ rx));
        }

        // ---- S^T = K * Q (3-term split) ----
        f32x4 s[2][NIN];
        #pragma unroll
        for (int jm = 0; jm < 2; ++jm)
            #pragma unroll
            for (int in_ = 0; in_ < NIN; ++in_) {
                f32x4 z = {0.f, 0.f, 0.f, 0.f};
                s[jm][in_] = z;
            }
        __builtin_amdgcn_s_setprio(1);
        #pragma unroll
        for (int jm = 0; jm < 2; ++jm)
            #pragma unroll
            for (int ks = 0; ks < 2; ++ks)
                #pragma unroll
                for (int in_ = 0; in_ < NIN; ++in_) {
                    s[jm][in_] = MFMA16(kf[jm][ks][0], qf[in_][ks][0], s[jm][in_]);
                    s[jm][in_] = MFMA16(kf[jm][ks][0], qf[in_][ks][1], s[jm][in_]);
                    s[jm][in_] = MFMA16(kf[jm][ks][1], qf[in_][ks][0], s[jm][in_]);
                }
        __builtin_amdgcn_s_setprio(0);

        // ---- online softmax with defer-max ----
        uint32_t pw[2][NIN][2];
        #pragma unroll
        for (int in_ = 0; in_ < NIN; ++in_) {
            float tmx = fmaxf(fmaxf(fmaxf(s[0][in_][0], s[0][in_][1]),
                                    fmaxf(s[0][in_][2], s[0][in_][3])),
                              fmaxf(fmaxf(s[1][in_][0], s[1][in_][1]),
                                    fmaxf(s[1][in_][2], s[1][in_][3])));
            tmx = fmaxf(tmx, __shfl_xor(tmx, 16, 64));
            tmx = fmaxf(tmx, __shfl_xor(tmx, 32, 64));
            const bool skip = __all(tmx <= mst[in_] + 1.0f);
            float mnew = skip ? mst[in_] : fmaxf(mst[in_], tmx);
            float rs = 0.f;
            #pragma unroll
            for (int jm = 0; jm < 2; ++jm)
                #pragma unroll
                for (int r = 0; r < 4; ++r) {
                    float p = exp2f(s[jm][in_][r] - mnew);
                    s[jm][in_][r] = p; rs += p;
                }
            rs += __shfl_xor(rs, 16, 64);
            rs += __shfl_xor(rs, 32, 64);
            if (skip) {
                lst[in_] += rs;
            } else {
                float fac = exp2f(mst[in_] - mnew);
                lst[in_] = lst[in_] * fac + rs;
                mst[in_] = mnew;
                #pragma unroll
                for (int cm = 0; cm < 4; ++cm) acc[cm][in_] *= fac;
            }
            #pragma unroll
            for (int jm = 0; jm < 2; ++jm) {
                pw[jm][in_][0] = pkh(s[jm][in_][0], s[jm][in_][1]);
                pw[jm][in_][1] = pkh(s[jm][in_][2], s[jm][in_][3]);
            }
        }

        // ---- P redistribution + O^T += V * P (2-term) ----
        #pragma unroll
        for (int in_ = 0; in_ < NIN; ++in_) {
            int w00 = (int)pw[0][in_][0], w01 = (int)pw[0][in_][1];
            int w10 = (int)pw[1][in_][0], w11 = (int)pw[1][in_][1];
            int a0 = __shfl(w00, idx0, 64), a1 = __shfl(w01, idx0, 64);
            int a2 = __shfl(w00, idx1, 64), a3 = __shfl(w01, idx1, 64);
            int b0 = __shfl(w10, idx0, 64), b1 = __shfl(w11, idx0, 64);
            int b2 = __shfl(w10, idx1, 64), b3 = __shfl(w11, idx1, 64);
            F8U fu;
            fu.u[0] = (uint32_t)(topTile ? b0 : a0);
            fu.u[1] = (uint32_t)(topTile ? b1 : a1);
            fu.u[2] = (uint32_t)(topTile ? b2 : a2);
            fu.u[3] = (uint32_t)(topTile ? b3 : a3);
            __builtin_amdgcn_s_setprio(1);
            #pragma unroll
            for (int cm = 0; cm < 4; ++cm) {
                acc[cm][in_] = MFMA16(vfh[cm], fu.v, acc[cm][in_]);
                acc[cm][in_] = MFMA16(vfl[cm], fu.v, acc[cm][in_]);
            }
            __builtin_amdgcn_s_setprio(0);
        }

        __syncthreads();   // drains staged loads (vmcnt) + all LDS reads
    }

    // epilogue: O/l -> interleaved fp16 hi/lo [h01,h23,l01,l23]
    #pragma unroll
    for (int in_ = 0; in_ < NIN; ++in_) {
        float inv = 1.0f / lst[in_];
        int i = i0 + 16 * in_ + ln;
        #pragma unroll
        for (int cm = 0; cm < 4; ++cm) {
            f32x4 o4 = acc[cm][in_] * inv;
            uint32_t h01, h23, l01, l23;
            split2(o4[0], o4[1], h01, l01);
            split2(o4[2], o4[3], h23, l23);
            u32x4 wv; wv[0] = h01; wv[1] = h23; wv[2] = l01; wv[3] = l23;
            size_t idx = ((size_t)b * P + i) * 512 + (size_t)(h * DH + 16 * cm + 4 * g);
            *reinterpret_cast<u32x4*>(ohl + idx) = wv;
        }
    }
}

// ---------------------------------------------------------------------------
// Output projection: out[b][o][i] = Wo[o][:] . O[b][i][:] + bo[o].
// 2-term fp16 MFMA. Wave = 32o x 32i -> 4096 waves.
// ---------------------------------------------------------------------------
__global__ __launch_bounds__(256, 4) void out_proj(
    const unsigned short* __restrict__ woh, const uint32_t* __restrict__ ohl,
    const float* __restrict__ bo, float* __restrict__ out)
{
    const int wid = threadIdx.x >> 6;
    const int l = threadIdx.x & 63;
    const int ln = l & 15, g = l >> 4;
    const int ibase = blockIdx.x * 128 + wid * 32;
    const int otile = blockIdx.y * 32;
    const int b = blockIdx.z;

    f32x4 acc[2][2];
    #pragma unroll
    for (int mt = 0; mt < 2; ++mt)
        #pragma unroll
        for (int nt = 0; nt < 2; ++nt) {
            f32x4 z = {0.f, 0.f, 0.f, 0.f};
            acc[mt][nt] = z;
        }

    #pragma unroll
    for (int ks = 0; ks < 16; ++ks) {
        const int c0 = 32 * ks + 8 * g;
        f16x8 wf[2];
        #pragma unroll
        for (int mt = 0; mt < 2; ++mt)
            wf[mt] = *reinterpret_cast<const f16x8*>(
                woh + (size_t)(otile + 16 * mt + ln) * HID + c0);
        #pragma unroll
        for (int nt = 0; nt < 2; ++nt) {
            const size_t obase = ((size_t)b * P + ibase + 16 * nt + ln) * 512 + c0;
            u32x4 A = *reinterpret_cast<const u32x4*>(ohl + obase);
            u32x4 Bv = *reinterpret_cast<const u32x4*>(ohl + obase + 4);
            F8U bh, bl;
            bh.u[0] = A[0]; bh.u[1] = A[1]; bh.u[2] = Bv[0]; bh.u[3] = Bv[1];
            bl.u[0] = A[2]; bl.u[1] = A[3]; bl.u[2] = Bv[2]; bl.u[3] = Bv[3];
            #pragma unroll
            for (int mt = 0; mt < 2; ++mt) {
                acc[mt][nt] = MFMA16(wf[mt], bh.v, acc[mt][nt]);
                acc[mt][nt] = MFMA16(wf[mt], bl.v, acc[mt][nt]);
            }
        }
    }

    #pragma unroll
    for (int mt = 0; mt < 2; ++mt)
        #pragma unroll
        for (int r = 0; r < 4; ++r) {
            int o_ = otile + 16 * mt + 4 * g + r;
            float bv = bo[o_];
            #pragma unroll
            for (int nt = 0; nt < 2; ++nt)
                out[((size_t)b * CQ + o_) * P + ibase + 16 * nt + ln] =
                    acc[mt][nt][r] + bv;
        }
}

extern "C" void kernel_launch(void* const* d_in, const int* in_sizes, int n_in,
                              void* d_out, int out_size, void* d_ws, size_t ws_size,
                              hipStream_t stream) {
    (void)in_sizes; (void)n_in; (void)out_size; (void)ws_size;
    const float* x   = (const float*)d_in[0];
    const float* ctx = (const float*)d_in[1];
    const float* Wq  = (const float*)d_in[2];
    const float* Wk  = (const float*)d_in[3];
    const float* Wv  = (const float*)d_in[4];
    const float* Wo  = (const float*)d_in[5];
    const float* bo  = (const float*)d_in[6];
    float* out = (float*)d_out;

    unsigned short* qh = (unsigned short*)d_ws;            // 8388608
    unsigned short* ql = qh + (size_t)8388608;
    unsigned short* kh = ql + (size_t)8388608;             // 2097152
    unsigned short* kl = kh + (size_t)2097152;
    unsigned short* vh = kl + (size_t)2097152;
    unsigned short* vl = vh + (size_t)2097152;
    unsigned short* woh = vl + (size_t)2097152;            // 131072
    uint32_t* ohl = (uint32_t*)(woh + (size_t)2 * 131072); // 8388608 u32, 16B-aligned

    dim3 blk(256);
    split_w<<<dim3(512), blk, 0, stream>>>(Wo, woh, CQ * HID);
    // Q = (QSCALE * Wq) @ x   -> [b][h][4096][64] fp16 hi/lo
    gemm_q<<<dim3(P / 64, HID / 64, BATCH), blk, 0, stream>>>(Wq, x, qh, ql);
    // K,V fused              -> K: [b][h][1024][64], V: [b][512][1024]
    gemm_kv<<<dim3(PC / 64, 16, BATCH), blk, 0, stream>>>(
        Wk, Wv, ctx, kh, kl, vh, vl);
    // attention -> ohl (fp16 hi/lo interleaved) [b][i][512]
    attn_mfma<<<dim3(HEADS * BATCH, P / 128), blk, 0, stream>>>(
        qh, ql, kh, kl, vh, vl, ohl);
    // out = Wo @ O + bo
    out_proj<<<dim3(P / 128, CQ / 32, BATCH), blk, 0, stream>>>(
        woh, ohl, bo, out);
}

// Round 9
// 283.512 us; speedup vs baseline: 1.4520x; 1.3569x over previous
//
#include <hip/hip_runtime.h>
#include <math.h>
#include <stdint.h>

// Problem dims (fixed)
#define BATCH 4
#define CQ 256      // x channels
#define P 4096      // query positions (64*64)
#define CC 512      // context channels
#define PC 1024     // kv positions (32*32)
#define HID 512     // HEADS*DIM_HEAD
#define HEADS 8
#define DH 64

// Fold attention scale 1/sqrt(64) * log2(e) into Q so softmax uses exp2.
#define QSCALE 0.180336880111113703f

typedef __attribute__((ext_vector_type(8))) __fp16 f16x8;
typedef __attribute__((ext_vector_type(2))) __fp16 f16x2;
typedef __attribute__((ext_vector_type(4))) float f32x4;
typedef __attribute__((ext_vector_type(4))) unsigned int u32x4;

union H2U { f16x2 h; uint32_t u; };
union F8U { uint32_t u[4]; f16x8 v; };

__device__ __forceinline__ uint32_t pkh(float a, float b) {
    H2U z; z.h = __builtin_amdgcn_cvt_pkrtz(a, b); return z.u;
}
__device__ __forceinline__ f16x2 upk(uint32_t w) { H2U z; z.u = w; return z.h; }
__device__ __forceinline__ void split2(float a, float b, uint32_t& hw, uint32_t& lw) {
    hw = pkh(a, b);
    f16x2 h = upk(hw);
    lw = pkh(a - (float)h[0], b - (float)h[1]);
}

#if __has_builtin(__builtin_amdgcn_exp2f)
#define EXP2(x) __builtin_amdgcn_exp2f(x)
#else
#define EXP2(x) exp2f(x)
#endif

#define MFMA16(a, b, c) __builtin_amdgcn_mfma_f32_16x16x32_f16(a, b, c, 0, 0, 0)

// async global -> LDS, 16B per lane. lds base must be wave-uniform.
__device__ __forceinline__ void gl_lds16(const unsigned short* g, unsigned short* l) {
    __builtin_amdgcn_global_load_lds(
        (const __attribute__((address_space(1))) unsigned int*)g,
        (__attribute__((address_space(3))) unsigned int*)l, 16, 0, 0);
}

// ---------------------------------------------------------------------------
// fp32 tiled GEMM for Q: C = Wq (MxK) * x[b] (KxN); epilogue writes split
// fp16 hi/lo to [b][h][pos][c64], scaled by QSCALE.
// ---------------------------------------------------------------------------
__global__ __launch_bounds__(256) void gemm_q(
    const float* __restrict__ A, const float* __restrict__ B,
    unsigned short* __restrict__ Dh, unsigned short* __restrict__ Dl)
{
    const int b = blockIdx.z;
    const int K = CQ, N = P;
    const float* Bb = B + (size_t)b * K * N;
    const int tn = blockIdx.x * 64;
    const int tm = blockIdx.y * 64;
    const int tid = threadIdx.x;
    const int tx = tid & 15, ty = tid >> 4;

    __shared__ float As[16][68];
    __shared__ float Bs[16][68];

    float acc[4][4] = {};

    for (int k0 = 0; k0 < K; k0 += 16) {
        {
            int m = tid >> 2;
            int kk = (tid & 3) * 4;
            const float4 a4 = *reinterpret_cast<const float4*>(
                &A[(size_t)(tm + m) * K + k0 + kk]);
            As[kk + 0][m] = a4.x; As[kk + 1][m] = a4.y;
            As[kk + 2][m] = a4.z; As[kk + 3][m] = a4.w;
        }
        {
            int kk = tid >> 4;
            int n = (tid & 15) * 4;
            *reinterpret_cast<float4*>(&Bs[kk][n]) =
                *reinterpret_cast<const float4*>(&Bb[(size_t)(k0 + kk) * N + tn + n]);
        }
        __syncthreads();
        #pragma unroll
        for (int kk = 0; kk < 16; ++kk) {
            float4 a = *reinterpret_cast<const float4*>(&As[kk][ty * 4]);
            float4 bv = *reinterpret_cast<const float4*>(&Bs[kk][tx * 4]);
            float av[4] = {a.x, a.y, a.z, a.w};
            float bb[4] = {bv.x, bv.y, bv.z, bv.w};
            #pragma unroll
            for (int i2 = 0; i2 < 4; ++i2)
                #pragma unroll
                for (int j2 = 0; j2 < 4; ++j2)
                    acc[i2][j2] = fmaf(av[i2], bb[j2], acc[i2][j2]);
        }
        __syncthreads();
    }

    const int h = tm >> 6;
    #pragma unroll
    for (int j2 = 0; j2 < 4; ++j2) {
        int pos = tn + tx * 4 + j2;
        uint32_t hw0, hw1, lw0, lw1;
        split2(QSCALE * acc[0][j2], QSCALE * acc[1][j2], hw0, lw0);
        split2(QSCALE * acc[2][j2], QSCALE * acc[3][j2], hw1, lw1);
        size_t off = (((size_t)b * HEADS + h) * (size_t)N + pos) * 64 + ty * 4;
        uint2 hh; hh.x = hw0; hh.y = hw1;
        uint2 ll; ll.x = lw0; ll.y = lw1;
        *reinterpret_cast<uint2*>(Dh + off) = hh;
        *reinterpret_cast<uint2*>(Dl + off) = ll;
    }
}

// ---------------------------------------------------------------------------
// Fused K+V projection: blockIdx.y selects weight/output. K -> [b][h][pos][64]
// (pos-major), V -> [b][c][pos] (channel-major). fp16 hi/lo epilogues.
// ---------------------------------------------------------------------------
__global__ __launch_bounds__(256) void gemm_kv(
    const float* __restrict__ Wk, const float* __restrict__ Wv,
    const float* __restrict__ B,
    unsigned short* __restrict__ Kh, unsigned short* __restrict__ Kl,
    unsigned short* __restrict__ Vh, unsigned short* __restrict__ Vl)
{
    const int b = blockIdx.z;
    const int K = CC, N = PC;
    const int sel = blockIdx.y >> 3;           // 0: K-proj, 1: V-proj
    const float* A = sel ? Wv : Wk;
    const float* Bb = B + (size_t)b * K * N;
    const int tn = blockIdx.x * 64;
    const int tm = (blockIdx.y & 7) * 64;
    const int tid = threadIdx.x;
    const int tx = tid & 15, ty = tid >> 4;

    __shared__ float As[16][68];
    __shared__ float Bs[16][68];

    float acc[4][4] = {};

    for (int k0 = 0; k0 < K; k0 += 16) {
        {
            int m = tid >> 2;
            int kk = (tid & 3) * 4;
            const float4 a4 = *reinterpret_cast<const float4*>(
                &A[(size_t)(tm + m) * K + k0 + kk]);
            As[kk + 0][m] = a4.x; As[kk + 1][m] = a4.y;
            As[kk + 2][m] = a4.z; As[kk + 3][m] = a4.w;
        }
        {
            int kk = tid >> 4;
            int n = (tid & 15) * 4;
            *reinterpret_cast<float4*>(&Bs[kk][n]) =
                *reinterpret_cast<const float4*>(&Bb[(size_t)(k0 + kk) * N + tn + n]);
        }
        __syncthreads();
        #pragma unroll
        for (int kk = 0; kk < 16; ++kk) {
            float4 a = *reinterpret_cast<const float4*>(&As[kk][ty * 4]);
            float4 bv = *reinterpret_cast<const float4*>(&Bs[kk][tx * 4]);
            float av[4] = {a.x, a.y, a.z, a.w};
            float bb[4] = {bv.x, bv.y, bv.z, bv.w};
            #pragma unroll
            for (int i2 = 0; i2 < 4; ++i2)
                #pragma unroll
                for (int j2 = 0; j2 < 4; ++j2)
                    acc[i2][j2] = fmaf(av[i2], bb[j2], acc[i2][j2]);
        }
        __syncthreads();
    }

    if (sel == 0) {
        const int h = tm >> 6;
        #pragma unroll
        for (int j2 = 0; j2 < 4; ++j2) {
            int pos = tn + tx * 4 + j2;
            uint32_t hw0, hw1, lw0, lw1;
            split2(acc[0][j2], acc[1][j2], hw0, lw0);
            split2(acc[2][j2], acc[3][j2], hw1, lw1);
            size_t off = (((size_t)b * HEADS + h) * (size_t)N + pos) * 64 + ty * 4;
            uint2 hh; hh.x = hw0; hh.y = hw1;
            uint2 ll; ll.x = lw0; ll.y = lw1;
            *reinterpret_cast<uint2*>(Kh + off) = hh;
            *reinterpret_cast<uint2*>(Kl + off) = ll;
        }
    } else {
        #pragma unroll
        for (int i2 = 0; i2 < 4; ++i2) {
            int c = tm + ty * 4 + i2;
            uint32_t hw0, hw1, lw0, lw1;
            split2(acc[i2][0], acc[i2][1], hw0, lw0);
            split2(acc[i2][2], acc[i2][3], hw1, lw1);
            size_t off = ((size_t)b * HID + c) * (size_t)N + tn + tx * 4;
            uint2 hh; hh.x = hw0; hh.y = hw1;
            uint2 ll; ll.x = lw0; ll.y = lw1;
            *reinterpret_cast<uint2*>(Vh + off) = hh;
            *reinterpret_cast<uint2*>(Vl + off) = ll;
        }
    }
}

// ---------------------------------------------------------------------------
// Split Wo into fp16 hi only (2-term output projection).
// ---------------------------------------------------------------------------
__global__ __launch_bounds__(256) void split_w(
    const float* __restrict__ W, unsigned short* __restrict__ Wh, int n)
{
    int i = blockIdx.x * 256 + threadIdx.x;
    if (i < n) Wh[i] = (unsigned short)(pkh(W[i], 0.f) & 0xffffu);
}

// ---------------------------------------------------------------------------
// Flash attention, split-fp16 MFMA. Wave = 64 queries (NIN=4), block = 4
// waves sharing LDS-staged K(hi,lo)+V(hi) per 32-j tile (12KB, dbuf).
// Cross-lane ops use __shfl (verified R4/R6). S = 3-term split,
// PV = 1-term (Vh only). Defer-max online softmax.
// ---------------------------------------------------------------------------
#define NIN 4
#define JBLK 32
#define NJT (PC / JBLK)

__global__ __launch_bounds__(256, 2) void attn_mfma(
    const unsigned short* __restrict__ qh, const unsigned short* __restrict__ ql,
    const unsigned short* __restrict__ kh, const unsigned short* __restrict__ kl,
    const unsigned short* __restrict__ vh,
    uint32_t* __restrict__ ohl)
{
    const int wid = threadIdx.x >> 6;
    const int l = threadIdx.x & 63;
    const int ln = l & 15, g = l >> 4;
    const int rx = ln & 7;
    const int hb = blockIdx.x;                 // (h, b) composite
    const int h = hb & 7, b = hb >> 3;
    const int i0 = (blockIdx.y * 4 + wid) * 64;

    const size_t qbase = (size_t)(b * HEADS + h) * P * 64;
    const size_t kbase = (size_t)(b * HEADS + h) * PC * 64;
    const size_t vbase = (size_t)(b * HID + h * DH) * PC;

    // per buf (6144 hw = 12KB): [0,2048) Kh 32 rows x 8 slots | [2048,4096) Kl
    // | [4096,6144) Vh 32 rows (2 chans each) x 8 slots. All slot-swizzled.
    __shared__ unsigned short smem[2][6144];

    // Q B-frags: lane holds q[i=i0+16in+ln][c=32ks+8g .. +7], hi/lo
    f16x8 qf[NIN][2][2];
    #pragma unroll
    for (int in_ = 0; in_ < NIN; ++in_) {
        const size_t qrow = qbase + (size_t)(i0 + 16 * in_ + ln) * 64 + 8 * g;
        #pragma unroll
        for (int ks = 0; ks < 2; ++ks) {
            qf[in_][ks][0] = *reinterpret_cast<const f16x8*>(qh + qrow + 32 * ks);
            qf[in_][ks][1] = *reinterpret_cast<const f16x8*>(ql + qrow + 32 * ks);
        }
    }

    f32x4 acc[4][NIN];
    #pragma unroll
    for (int cm = 0; cm < 4; ++cm)
        #pragma unroll
        for (int in_ = 0; in_ < NIN; ++in_) {
            f32x4 z = {0.f, 0.f, 0.f, 0.f};
            acc[cm][in_] = z;
        }
    float mst[NIN], lst[NIN];
    #pragma unroll
    for (int in_ = 0; in_ < NIN; ++in_) { mst[in_] = -1e30f; lst[in_] = 0.f; }

    const int idx0 = ln + 16 * (2 * (g & 1));
    const int idx1 = idx0 + 16;
    const bool topTile = (g & 2) != 0;

    // ---- staging: 12 segs of 1KB; wave stages segs wid*3 .. wid*3+2 ----
    auto stage = [&](int buf, int jt) {
        const int j0 = jt * JBLK;
        #pragma unroll
        for (int t = 0; t < 3; ++t) {
            const int s = wid * 3 + t;
            unsigned short* lbase = &smem[buf][s * 512];
            const int i = (s & 3) * 64 + l;
            const int row = i >> 3, p = i & 7;
            const int slog = p ^ (row & 7);
            const unsigned short* src;
            if (s < 4) {
                src = kh + kbase + (size_t)(j0 + row) * 64 + 8 * slog;
            } else if (s < 8) {
                src = kl + kbase + (size_t)(j0 + row) * 64 + 8 * slog;
            } else {
                const int c = 2 * row + (slog >> 2);
                src = vh + vbase + (size_t)c * PC + j0 + 8 * (slog & 3);
            }
            gl_lds16(src, lbase);
        }
    };

    stage(0, 0);
    __syncthreads();

    for (int jt = 0; jt < NJT; ++jt) {
        const int cur = jt & 1;
        if (jt + 1 < NJT) stage(cur ^ 1, jt + 1);
        const unsigned short* sm = &smem[cur][0];

        // ---- K frags from LDS (swizzled) ----
        f16x8 kf[2][2][2];
        #pragma unroll
        for (int jm = 0; jm < 2; ++jm)
            #pragma unroll
            for (int ks = 0; ks < 2; ++ks) {
                const int base = (16 * jm + ln) * 64 + 8 * ((4 * ks + g) ^ rx);
                kf[jm][ks][0] = *reinterpret_cast<const f16x8*>(sm + base);
                kf[jm][ks][1] = *reinterpret_cast<const f16x8*>(sm + 2048 + base);
            }
        // ---- V frags from LDS (swizzled, hi only) ----
        f16x8 vf[4];
        #pragma unroll
        for (int cm = 0; cm < 4; ++cm) {
            const int vaddr = 4096 + (8 * cm + (ln >> 1)) * 64 +
                              8 * ((4 * (ln & 1) + g) ^ (ln >> 1));
            vf[cm] = *reinterpret_cast<const f16x8*>(sm + vaddr);
        }

        // ---- S^T = K * Q (3-term split) ----
        f32x4 s[2][NIN];
        #pragma unroll
        for (int jm = 0; jm < 2; ++jm)
            #pragma unroll
            for (int in_ = 0; in_ < NIN; ++in_) {
                f32x4 z = {0.f, 0.f, 0.f, 0.f};
                s[jm][in_] = z;
            }
        __builtin_amdgcn_s_setprio(1);
        #pragma unroll
        for (int jm = 0; jm < 2; ++jm)
            #pragma unroll
            for (int ks = 0; ks < 2; ++ks)
                #pragma unroll
                for (int in_ = 0; in_ < NIN; ++in_) {
                    s[jm][in_] = MFMA16(kf[jm][ks][0], qf[in_][ks][0], s[jm][in_]);
                    s[jm][in_] = MFMA16(kf[jm][ks][0], qf[in_][ks][1], s[jm][in_]);
                    s[jm][in_] = MFMA16(kf[jm][ks][1], qf[in_][ks][0], s[jm][in_]);
                }
        __builtin_amdgcn_s_setprio(0);

        // ---- per query-group: softmax (defer-max) + redistribute + PV ----
        #pragma unroll
        for (int in_ = 0; in_ < NIN; ++in_) {
            float tmx = fmaxf(fmaxf(fmaxf(s[0][in_][0], s[0][in_][1]),
                                    fmaxf(s[0][in_][2], s[0][in_][3])),
                              fmaxf(fmaxf(s[1][in_][0], s[1][in_][1]),
                                    fmaxf(s[1][in_][2], s[1][in_][3])));
            tmx = fmaxf(tmx, __shfl_xor(tmx, 16, 64));
            tmx = fmaxf(tmx, __shfl_xor(tmx, 32, 64));
            const bool skip = __all(tmx <= mst[in_] + 1.0f);
            float mnew = skip ? mst[in_] : fmaxf(mst[in_], tmx);
            float rs = 0.f;
            #pragma unroll
            for (int jm = 0; jm < 2; ++jm)
                #pragma unroll
                for (int r = 0; r < 4; ++r) {
                    float p = EXP2(s[jm][in_][r] - mnew);
                    s[jm][in_][r] = p; rs += p;
                }
            rs += __shfl_xor(rs, 16, 64);
            rs += __shfl_xor(rs, 32, 64);
            if (skip) {
                lst[in_] += rs;
            } else {
                float fac = EXP2(mst[in_] - mnew);
                lst[in_] = lst[in_] * fac + rs;
                mst[in_] = mnew;
                #pragma unroll
                for (int cm = 0; cm < 4; ++cm) acc[cm][in_] *= fac;
            }

            // pack P rows -> words W[jm][c]: c0 = rows(0,1), c1 = rows(2,3)
            int w00 = (int)pkh(s[0][in_][0], s[0][in_][1]);
            int w01 = (int)pkh(s[0][in_][2], s[0][in_][3]);
            int w10 = (int)pkh(s[1][in_][0], s[1][in_][1]);
            int w11 = (int)pkh(s[1][in_][2], s[1][in_][3]);

            // D-frag -> B-frag redistribution (shfl form, verified R4/R6)
            int a0 = __shfl(w00, idx0, 64), a1 = __shfl(w01, idx0, 64);
            int a2 = __shfl(w00, idx1, 64), a3 = __shfl(w01, idx1, 64);
            int b0 = __shfl(w10, idx0, 64), b1 = __shfl(w11, idx0, 64);
            int b2 = __shfl(w10, idx1, 64), b3 = __shfl(w11, idx1, 64);
            F8U fu;
            fu.u[0] = (uint32_t)(topTile ? b0 : a0);
            fu.u[1] = (uint32_t)(topTile ? b1 : a1);
            fu.u[2] = (uint32_t)(topTile ? b2 : a2);
            fu.u[3] = (uint32_t)(topTile ? b3 : a3);

            __builtin_amdgcn_s_setprio(1);
            #pragma unroll
            for (int cm = 0; cm < 4; ++cm)
                acc[cm][in_] = MFMA16(vf[cm], fu.v, acc[cm][in_]);
            __builtin_amdgcn_s_setprio(0);
        }

        __syncthreads();   // drains staged loads + all LDS reads of buf[cur]
    }

    // epilogue: O/l -> interleaved fp16 hi/lo [h01,h23,l01,l23]
    #pragma unroll
    for (int in_ = 0; in_ < NIN; ++in_) {
        float inv = 1.0f / lst[in_];
        int i = i0 + 16 * in_ + ln;
        #pragma unroll
        for (int cm = 0; cm < 4; ++cm) {
            f32x4 o4 = acc[cm][in_] * inv;
            uint32_t h01, h23, l01, l23;
            split2(o4[0], o4[1], h01, l01);
            split2(o4[2], o4[3], h23, l23);
            u32x4 wv; wv[0] = h01; wv[1] = h23; wv[2] = l01; wv[3] = l23;
            size_t idx = ((size_t)b * P + i) * 512 + (size_t)(h * DH + 16 * cm + 4 * g);
            *reinterpret_cast<u32x4*>(ohl + idx) = wv;
        }
    }
}

// ---------------------------------------------------------------------------
// Output projection: out[b][o][i] = Wo[o][:] . O[b][i][:] + bo[o].
// 2-term fp16 MFMA. Wave = 32o x 32i -> 4096 waves.
// ---------------------------------------------------------------------------
__global__ __launch_bounds__(256, 4) void out_proj(
    const unsigned short* __restrict__ woh, const uint32_t* __restrict__ ohl,
    const float* __restrict__ bo, float* __restrict__ out)
{
    const int wid = threadIdx.x >> 6;
    const int l = threadIdx.x & 63;
    const int ln = l & 15, g = l >> 4;
    const int ibase = blockIdx.x * 128 + wid * 32;
    const int otile = blockIdx.y * 32;
    const int b = blockIdx.z;

    f32x4 acc[2][2];
    #pragma unroll
    for (int mt = 0; mt < 2; ++mt)
        #pragma unroll
        for (int nt = 0; nt < 2; ++nt) {
            f32x4 z = {0.f, 0.f, 0.f, 0.f};
            acc[mt][nt] = z;
        }

    #pragma unroll
    for (int ks = 0; ks < 16; ++ks) {
        const int c0 = 32 * ks + 8 * g;
        f16x8 wf[2];
        #pragma unroll
        for (int mt = 0; mt < 2; ++mt)
            wf[mt] = *reinterpret_cast<const f16x8*>(
                woh + (size_t)(otile + 16 * mt + ln) * HID + c0);
        #pragma unroll
        for (int nt = 0; nt < 2; ++nt) {
            const size_t obase = ((size_t)b * P + ibase + 16 * nt + ln) * 512 + c0;
            u32x4 A = *reinterpret_cast<const u32x4*>(ohl + obase);
            u32x4 Bv = *reinterpret_cast<const u32x4*>(ohl + obase + 4);
            F8U bh, bl;
            bh.u[0] = A[0]; bh.u[1] = A[1]; bh.u[2] = Bv[0]; bh.u[3] = Bv[1];
            bl.u[0] = A[2]; bl.u[1] = A[3]; bl.u[2] = Bv[2]; bl.u[3] = Bv[3];
            #pragma unroll
            for (int mt = 0; mt < 2; ++mt) {
                acc[mt][nt] = MFMA16(wf[mt], bh.v, acc[mt][nt]);
                acc[mt][nt] = MFMA16(wf[mt], bl.v, acc[mt][nt]);
            }
        }
    }

    #pragma unroll
    for (int mt = 0; mt < 2; ++mt)
        #pragma unroll
        for (int r = 0; r < 4; ++r) {
            int o_ = otile + 16 * mt + 4 * g + r;
            float bv = bo[o_];
            #pragma unroll
            for (int nt = 0; nt < 2; ++nt)
                out[((size_t)b * CQ + o_) * P + ibase + 16 * nt + ln] =
                    acc[mt][nt][r] + bv;
        }
}

extern "C" void kernel_launch(void* const* d_in, const int* in_sizes, int n_in,
                              void* d_out, int out_size, void* d_ws, size_t ws_size,
                              hipStream_t stream) {
    (void)in_sizes; (void)n_in; (void)out_size; (void)ws_size;
    const float* x   = (const float*)d_in[0];
    const float* ctx = (const float*)d_in[1];
    const float* Wq  = (const float*)d_in[2];
    const float* Wk  = (const float*)d_in[3];
    const float* Wv  = (const float*)d_in[4];
    const float* Wo  = (const float*)d_in[5];
    const float* bo  = (const float*)d_in[6];
    float* out = (float*)d_out;

    unsigned short* qh = (unsigned short*)d_ws;            // 8388608
    unsigned short* ql = qh + (size_t)8388608;
    unsigned short* kh = ql + (size_t)8388608;             // 2097152
    unsigned short* kl = kh + (size_t)2097152;
    unsigned short* vh = kl + (size_t)2097152;
    unsigned short* vl = vh + (size_t)2097152;             // written, unused by attn
    unsigned short* woh = vl + (size_t)2097152;            // 131072
    uint32_t* ohl = (uint32_t*)(woh + (size_t)2 * 131072); // 8388608 u32, 16B-aligned

    dim3 blk(256);
    split_w<<<dim3(512), blk, 0, stream>>>(Wo, woh, CQ * HID);
    // Q = (QSCALE * Wq) @ x   -> [b][h][4096][64] fp16 hi/lo
    gemm_q<<<dim3(P / 64, HID / 64, BATCH), blk, 0, stream>>>(Wq, x, qh, ql);
    // K,V fused              -> K: [b][h][1024][64], V: [b][512][1024]
    gemm_kv<<<dim3(PC / 64, 16, BATCH), blk, 0, stream>>>(
        Wk, Wv, ctx, kh, kl, vh, vl);
    // attention -> ohl (fp16 hi/lo interleaved) [b][i][512]
    attn_mfma<<<dim3(HEADS * BATCH, P / 256), blk, 0, stream>>>(
        qh, ql, kh, kl, vh, ohl);
    // out = Wo @ O + bo
    out_proj<<<dim3(P / 128, CQ / 32, BATCH), blk, 0, stream>>>(
        woh, ohl, bo, out);
}

// Round 10
// 268.090 us; speedup vs baseline: 1.5356x; 1.0575x over previous
//
#include <hip/hip_runtime.h>
#include <math.h>
#include <stdint.h>

// Problem dims (fixed)
#define BATCH 4
#define CQ 256      // x channels
#define P 4096      // query positions (64*64)
#define CC 512      // context channels
#define PC 1024     // kv positions (32*32)
#define HID 512     // HEADS*DIM_HEAD
#define HEADS 8
#define DH 64

// Fold attention scale 1/sqrt(64) * log2(e) into Q so softmax uses exp2.
#define QSCALE 0.180336880111113703f

typedef __attribute__((ext_vector_type(8))) __fp16 f16x8;
typedef __attribute__((ext_vector_type(2))) __fp16 f16x2;
typedef __attribute__((ext_vector_type(4))) float f32x4;
typedef __attribute__((ext_vector_type(4))) unsigned int u32x4;

union H2U { f16x2 h; uint32_t u; };
union F8U { uint32_t u[4]; f16x8 v; };

__device__ __forceinline__ uint32_t pkh(float a, float b) {
    H2U z; z.h = __builtin_amdgcn_cvt_pkrtz(a, b); return z.u;
}
__device__ __forceinline__ f16x2 upk(uint32_t w) { H2U z; z.u = w; return z.h; }
__device__ __forceinline__ void split2(float a, float b, uint32_t& hw, uint32_t& lw) {
    hw = pkh(a, b);
    f16x2 h = upk(hw);
    lw = pkh(a - (float)h[0], b - (float)h[1]);
}
__device__ __forceinline__ void split1(float f, unsigned short& h, unsigned short& l) {
    uint32_t hw = pkh(f, 0.f);
    h = (unsigned short)(hw & 0xffffu);
    H2U z; z.u = hw;
    l = (unsigned short)(pkh(f - (float)z.h[0], 0.f) & 0xffffu);
}

#if __has_builtin(__builtin_amdgcn_exp2f)
#define EXP2(x) __builtin_amdgcn_exp2f(x)
#else
#define EXP2(x) exp2f(x)
#endif

#define MFMA16(a, b, c) __builtin_amdgcn_mfma_f32_16x16x32_f16(a, b, c, 0, 0, 0)

// async global -> LDS, 16B per lane. lds base must be wave-uniform.
__device__ __forceinline__ void gl_lds16(const unsigned short* g, unsigned short* l) {
    __builtin_amdgcn_global_load_lds(
        (const __attribute__((address_space(1))) unsigned int*)g,
        (__attribute__((address_space(3))) unsigned int*)l, 16, 0, 0);
}

// ---------------------------------------------------------------------------
// Split all weights once: wq (xQSCALE) hi/lo, wk hi/lo, wv hi/lo, wo hi.
// Grid: 3072 blocks x 256.
// ---------------------------------------------------------------------------
__global__ __launch_bounds__(256) void split_all(
    const float* __restrict__ Wq, const float* __restrict__ Wk,
    const float* __restrict__ Wv, const float* __restrict__ Wo,
    unsigned short* __restrict__ wqh, unsigned short* __restrict__ wql,
    unsigned short* __restrict__ wkh, unsigned short* __restrict__ wkl,
    unsigned short* __restrict__ wvh, unsigned short* __restrict__ wvl,
    unsigned short* __restrict__ woh)
{
    const int bid = blockIdx.x;
    const int t = threadIdx.x;
    if (bid < 512) {
        int i = bid * 256 + t;
        split1(QSCALE * Wq[i], wqh[i], wql[i]);
    } else if (bid < 1536) {
        int i = (bid - 512) * 256 + t;
        split1(Wk[i], wkh[i], wkl[i]);
    } else if (bid < 2560) {
        int i = (bid - 1536) * 256 + t;
        split1(Wv[i], wvh[i], wvl[i]);
    } else {
        int i = (bid - 2560) * 256 + t;
        woh[i] = (unsigned short)(pkh(Wo[i], 0.f) & 0xffffu);
    }
}

// ---------------------------------------------------------------------------
// Transpose-split: in [b][C][Npos] f32 -> Dh/Dl [b][pos][C] fp16 hi/lo.
// 64x64 LDS tile. Grid: (Npos/64, C/64, B).
// ---------------------------------------------------------------------------
__global__ __launch_bounds__(256) void split_tr(
    const float* __restrict__ in,
    unsigned short* __restrict__ Dh, unsigned short* __restrict__ Dl,
    int C, int Npos)
{
    const int b = blockIdx.z;
    const int p0 = blockIdx.x * 64;
    const int c0 = blockIdx.y * 64;
    const int tid = threadIdx.x;
    const int tx = tid & 15, ty = tid >> 4;
    const float* src = in + (size_t)b * C * Npos;

    __shared__ float Ls[64][65];

    #pragma unroll
    for (int it = 0; it < 4; ++it) {
        const int cl = 16 * it + ty;
        float4 v = *reinterpret_cast<const float4*>(
            &src[(size_t)(c0 + cl) * Npos + p0 + 4 * tx]);
        Ls[cl][4 * tx + 0] = v.x; Ls[cl][4 * tx + 1] = v.y;
        Ls[cl][4 * tx + 2] = v.z; Ls[cl][4 * tx + 3] = v.w;
    }
    __syncthreads();
    #pragma unroll
    for (int it = 0; it < 4; ++it) {
        const int pl = 16 * it + ty;
        const int cc = 4 * tx;
        float v0 = Ls[cc + 0][pl], v1 = Ls[cc + 1][pl];
        float v2 = Ls[cc + 2][pl], v3 = Ls[cc + 3][pl];
        uint32_t hw0, hw1, lw0, lw1;
        split2(v0, v1, hw0, lw0);
        split2(v2, v3, hw1, lw1);
        size_t off = ((size_t)b * Npos + p0 + pl) * C + c0 + cc;
        uint2 hh; hh.x = hw0; hh.y = hw1;
        uint2 ll; ll.x = lw0; ll.y = lw1;
        *reinterpret_cast<uint2*>(Dh + off) = hh;
        *reinterpret_cast<uint2*>(Dl + off) = ll;
    }
}

// ---------------------------------------------------------------------------
// Q projection, 3-term split-fp16 MFMA: Q = (QSCALE*Wq) @ x.
// A = wq [512][256] split, B = x-split [b][4096][256]. Block 128M x 64N,
// wave 64M x 32N. Out: qh/ql [b][h][pos][64].
// ---------------------------------------------------------------------------
__global__ __launch_bounds__(256) void proj_q(
    const unsigned short* __restrict__ ah_, const unsigned short* __restrict__ al_,
    const unsigned short* __restrict__ xh_, const unsigned short* __restrict__ xl_,
    unsigned short* __restrict__ qh_, unsigned short* __restrict__ ql_)
{
    const int b = blockIdx.z;
    const int tileM = blockIdx.y * 128;
    const int n0 = blockIdx.x * 64;
    const int wid = threadIdx.x >> 6;
    const int l = threadIdx.x & 63;
    const int ln = l & 15, g = l >> 4;
    const int mb = tileM + 64 * (wid & 1);
    const int nb = n0 + 32 * (wid >> 1);

    f32x4 acc[4][2];
    #pragma unroll
    for (int mt = 0; mt < 4; ++mt)
        #pragma unroll
        for (int nt = 0; nt < 2; ++nt) {
            f32x4 z = {0.f, 0.f, 0.f, 0.f};
            acc[mt][nt] = z;
        }

    #pragma unroll
    for (int k0 = 0; k0 < CQ; k0 += 32) {
        f16x8 ah[4], al[4], bh[2], bl[2];
        #pragma unroll
        for (int mt = 0; mt < 4; ++mt) {
            const size_t off = (size_t)(mb + 16 * mt + ln) * CQ + k0 + 8 * g;
            ah[mt] = *reinterpret_cast<const f16x8*>(ah_ + off);
            al[mt] = *reinterpret_cast<const f16x8*>(al_ + off);
        }
        #pragma unroll
        for (int nt = 0; nt < 2; ++nt) {
            const size_t off = ((size_t)b * P + nb + 16 * nt + ln) * CQ + k0 + 8 * g;
            bh[nt] = *reinterpret_cast<const f16x8*>(xh_ + off);
            bl[nt] = *reinterpret_cast<const f16x8*>(xl_ + off);
        }
        #pragma unroll
        for (int mt = 0; mt < 4; ++mt)
            #pragma unroll
            for (int nt = 0; nt < 2; ++nt) {
                acc[mt][nt] = MFMA16(ah[mt], bh[nt], acc[mt][nt]);
                acc[mt][nt] = MFMA16(ah[mt], bl[nt], acc[mt][nt]);
                acc[mt][nt] = MFMA16(al[mt], bh[nt], acc[mt][nt]);
            }
    }

    #pragma unroll
    for (int mt = 0; mt < 4; ++mt) {
        const int m0 = mb + 16 * mt + 4 * g;
        const int h = m0 >> 6, cl = m0 & 63;
        #pragma unroll
        for (int nt = 0; nt < 2; ++nt) {
            const int pos = nb + 16 * nt + ln;
            uint32_t hw0, hw1, lw0, lw1;
            split2(acc[mt][nt][0], acc[mt][nt][1], hw0, lw0);
            split2(acc[mt][nt][2], acc[mt][nt][3], hw1, lw1);
            const size_t base = (((size_t)b * HEADS + h) * P + pos) * 64 + cl;
            uint2 hh; hh.x = hw0; hh.y = hw1;
            uint2 ll; ll.x = lw0; ll.y = lw1;
            *reinterpret_cast<uint2*>(qh_ + base) = hh;
            *reinterpret_cast<uint2*>(ql_ + base) = ll;
        }
    }
}

// ---------------------------------------------------------------------------
// K+V projection, 3-term split-fp16 MFMA over ctx-split [b][1024][512].
// blockIdx.y: 0..3 -> K rows 128y (out kh/kl [b][h][pos][64]);
//             4..7 -> V rows 128(y-4) (out vh [b][c][pos], hi only).
// ---------------------------------------------------------------------------
__global__ __launch_bounds__(256) void proj_kv(
    const unsigned short* __restrict__ wkh_, const unsigned short* __restrict__ wkl_,
    const unsigned short* __restrict__ wvh_, const unsigned short* __restrict__ wvl_,
    const unsigned short* __restrict__ ch_, const unsigned short* __restrict__ cl_,
    unsigned short* __restrict__ kh_, unsigned short* __restrict__ kl_,
    unsigned short* __restrict__ vh_)
{
    const int b = blockIdx.z;
    const int my = blockIdx.y;
    const bool isV = my >= 4;
    const int tileM = (my & 3) * 128;
    const int n0 = blockIdx.x * 64;
    const int wid = threadIdx.x >> 6;
    const int l = threadIdx.x & 63;
    const int ln = l & 15, g = l >> 4;
    const int mb = tileM + 64 * (wid & 1);
    const int nb = n0 + 32 * (wid >> 1);

    const unsigned short* Ah = isV ? wvh_ : wkh_;
    const unsigned short* Al = isV ? wvl_ : wkl_;

    f32x4 acc[4][2];
    #pragma unroll
    for (int mt = 0; mt < 4; ++mt)
        #pragma unroll
        for (int nt = 0; nt < 2; ++nt) {
            f32x4 z = {0.f, 0.f, 0.f, 0.f};
            acc[mt][nt] = z;
        }

    #pragma unroll 4
    for (int k0 = 0; k0 < CC; k0 += 32) {
        f16x8 ah[4], al[4], bh[2], bl[2];
        #pragma unroll
        for (int mt = 0; mt < 4; ++mt) {
            const size_t off = (size_t)(mb + 16 * mt + ln) * CC + k0 + 8 * g;
            ah[mt] = *reinterpret_cast<const f16x8*>(Ah + off);
            al[mt] = *reinterpret_cast<const f16x8*>(Al + off);
        }
        #pragma unroll
        for (int nt = 0; nt < 2; ++nt) {
            const size_t off = ((size_t)b * PC + nb + 16 * nt + ln) * CC + k0 + 8 * g;
            bh[nt] = *reinterpret_cast<const f16x8*>(ch_ + off);
            bl[nt] = *reinterpret_cast<const f16x8*>(cl_ + off);
        }
        #pragma unroll
        for (int mt = 0; mt < 4; ++mt)
            #pragma unroll
            for (int nt = 0; nt < 2; ++nt) {
                acc[mt][nt] = MFMA16(ah[mt], bh[nt], acc[mt][nt]);
                acc[mt][nt] = MFMA16(ah[mt], bl[nt], acc[mt][nt]);
                acc[mt][nt] = MFMA16(al[mt], bh[nt], acc[mt][nt]);
            }
    }

    if (!isV) {
        #pragma unroll
        for (int mt = 0; mt < 4; ++mt) {
            const int m0 = mb + 16 * mt + 4 * g;
            const int h = m0 >> 6, cl2 = m0 & 63;
            #pragma unroll
            for (int nt = 0; nt < 2; ++nt) {
                const int pos = nb + 16 * nt + ln;
                uint32_t hw0, hw1, lw0, lw1;
                split2(acc[mt][nt][0], acc[mt][nt][1], hw0, lw0);
                split2(acc[mt][nt][2], acc[mt][nt][3], hw1, lw1);
                const size_t base = (((size_t)b * HEADS + h) * PC + pos) * 64 + cl2;
                uint2 hh; hh.x = hw0; hh.y = hw1;
                uint2 ll; ll.x = lw0; ll.y = lw1;
                *reinterpret_cast<uint2*>(kh_ + base) = hh;
                *reinterpret_cast<uint2*>(kl_ + base) = ll;
            }
        }
    } else {
        #pragma unroll
        for (int mt = 0; mt < 4; ++mt) {
            const int m0 = mb + 16 * mt + 4 * g;   // V channel 0..511
            #pragma unroll
            for (int nt = 0; nt < 2; ++nt) {
                const int pos = nb + 16 * nt + ln;
                #pragma unroll
                for (int r = 0; r < 4; ++r) {
                    unsigned short hv =
                        (unsigned short)(pkh(acc[mt][nt][r], 0.f) & 0xffffu);
                    vh_[((size_t)b * HID + m0 + r) * PC + pos] = hv;
                }
            }
        }
    }
}

// ---------------------------------------------------------------------------
// Flash attention, split-fp16 MFMA. Wave = 64 queries (NIN=4), block = 4
// waves sharing LDS-staged K(hi,lo)+V(hi) per 32-j tile (12KB, dbuf).
// Cross-lane ops use __shfl (verified R4/R6). S = 3-term split,
// PV = 1-term (Vh only). Defer-max online softmax.  (unchanged from R9)
// ---------------------------------------------------------------------------
#define NIN 4
#define JBLK 32
#define NJT (PC / JBLK)

__global__ __launch_bounds__(256, 2) void attn_mfma(
    const unsigned short* __restrict__ qh, const unsigned short* __restrict__ ql,
    const unsigned short* __restrict__ kh, const unsigned short* __restrict__ kl,
    const unsigned short* __restrict__ vh,
    uint32_t* __restrict__ ohl)
{
    const int wid = threadIdx.x >> 6;
    const int l = threadIdx.x & 63;
    const int ln = l & 15, g = l >> 4;
    const int rx = ln & 7;
    const int hb = blockIdx.x;                 // (h, b) composite
    const int h = hb & 7, b = hb >> 3;
    const int i0 = (blockIdx.y * 4 + wid) * 64;

    const size_t qbase = (size_t)(b * HEADS + h) * P * 64;
    const size_t kbase = (size_t)(b * HEADS + h) * PC * 64;
    const size_t vbase = (size_t)(b * HID + h * DH) * PC;

    __shared__ unsigned short smem[2][6144];

    f16x8 qf[NIN][2][2];
    #pragma unroll
    for (int in_ = 0; in_ < NIN; ++in_) {
        const size_t qrow = qbase + (size_t)(i0 + 16 * in_ + ln) * 64 + 8 * g;
        #pragma unroll
        for (int ks = 0; ks < 2; ++ks) {
            qf[in_][ks][0] = *reinterpret_cast<const f16x8*>(qh + qrow + 32 * ks);
            qf[in_][ks][1] = *reinterpret_cast<const f16x8*>(ql + qrow + 32 * ks);
        }
    }

    f32x4 acc[4][NIN];
    #pragma unroll
    for (int cm = 0; cm < 4; ++cm)
        #pragma unroll
        for (int in_ = 0; in_ < NIN; ++in_) {
            f32x4 z = {0.f, 0.f, 0.f, 0.f};
            acc[cm][in_] = z;
        }
    float mst[NIN], lst[NIN];
    #pragma unroll
    for (int in_ = 0; in_ < NIN; ++in_) { mst[in_] = -1e30f; lst[in_] = 0.f; }

    const int idx0 = ln + 16 * (2 * (g & 1));
    const int idx1 = idx0 + 16;
    const bool topTile = (g & 2) != 0;

    auto stage = [&](int buf, int jt) {
        const int j0 = jt * JBLK;
        #pragma unroll
        for (int t = 0; t < 3; ++t) {
            const int s = wid * 3 + t;
            unsigned short* lbase = &smem[buf][s * 512];
            const int i = (s & 3) * 64 + l;
            const int row = i >> 3, p = i & 7;
            const int slog = p ^ (row & 7);
            const unsigned short* src;
            if (s < 4) {
                src = kh + kbase + (size_t)(j0 + row) * 64 + 8 * slog;
            } else if (s < 8) {
                src = kl + kbase + (size_t)(j0 + row) * 64 + 8 * slog;
            } else {
                const int c = 2 * row + (slog >> 2);
                src = vh + vbase + (size_t)c * PC + j0 + 8 * (slog & 3);
            }
            gl_lds16(src, lbase);
        }
    };

    stage(0, 0);
    __syncthreads();

    for (int jt = 0; jt < NJT; ++jt) {
        const int cur = jt & 1;
        if (jt + 1 < NJT) stage(cur ^ 1, jt + 1);
        const unsigned short* sm = &smem[cur][0];

        f16x8 kf[2][2][2];
        #pragma unroll
        for (int jm = 0; jm < 2; ++jm)
            #pragma unroll
            for (int ks = 0; ks < 2; ++ks) {
                const int base = (16 * jm + ln) * 64 + 8 * ((4 * ks + g) ^ rx);
                kf[jm][ks][0] = *reinterpret_cast<const f16x8*>(sm + base);
                kf[jm][ks][1] = *reinterpret_cast<const f16x8*>(sm + 2048 + base);
            }
        f16x8 vf[4];
        #pragma unroll
        for (int cm = 0; cm < 4; ++cm) {
            const int vaddr = 4096 + (8 * cm + (ln >> 1)) * 64 +
                              8 * ((4 * (ln & 1) + g) ^ (ln >> 1));
            vf[cm] = *reinterpret_cast<const f16x8*>(sm + vaddr);
        }

        f32x4 s[2][NIN];
        #pragma unroll
        for (int jm = 0; jm < 2; ++jm)
            #pragma unroll
            for (int in_ = 0; in_ < NIN; ++in_) {
                f32x4 z = {0.f, 0.f, 0.f, 0.f};
                s[jm][in_] = z;
            }
        __builtin_amdgcn_s_setprio(1);
        #pragma unroll
        for (int jm = 0; jm < 2; ++jm)
            #pragma unroll
            for (int ks = 0; ks < 2; ++ks)
                #pragma unroll
                for (int in_ = 0; in_ < NIN; ++in_) {
                    s[jm][in_] = MFMA16(kf[jm][ks][0], qf[in_][ks][0], s[jm][in_]);
                    s[jm][in_] = MFMA16(kf[jm][ks][0], qf[in_][ks][1], s[jm][in_]);
                    s[jm][in_] = MFMA16(kf[jm][ks][1], qf[in_][ks][0], s[jm][in_]);
                }
        __builtin_amdgcn_s_setprio(0);

        #pragma unroll
        for (int in_ = 0; in_ < NIN; ++in_) {
            float tmx = fmaxf(fmaxf(fmaxf(s[0][in_][0], s[0][in_][1]),
                                    fmaxf(s[0][in_][2], s[0][in_][3])),
                              fmaxf(fmaxf(s[1][in_][0], s[1][in_][1]),
                                    fmaxf(s[1][in_][2], s[1][in_][3])));
            tmx = fmaxf(tmx, __shfl_xor(tmx, 16, 64));
            tmx = fmaxf(tmx, __shfl_xor(tmx, 32, 64));
            const bool skip = __all(tmx <= mst[in_] + 1.0f);
            float mnew = skip ? mst[in_] : fmaxf(mst[in_], tmx);
            float rs = 0.f;
            #pragma unroll
            for (int jm = 0; jm < 2; ++jm)
                #pragma unroll
                for (int r = 0; r < 4; ++r) {
                    float p = EXP2(s[jm][in_][r] - mnew);
                    s[jm][in_][r] = p; rs += p;
                }
            rs += __shfl_xor(rs, 16, 64);
            rs += __shfl_xor(rs, 32, 64);
            if (skip) {
                lst[in_] += rs;
            } else {
                float fac = EXP2(mst[in_] - mnew);
                lst[in_] = lst[in_] * fac + rs;
                mst[in_] = mnew;
                #pragma unroll
                for (int cm = 0; cm < 4; ++cm) acc[cm][in_] *= fac;
            }

            int w00 = (int)pkh(s[0][in_][0], s[0][in_][1]);
            int w01 = (int)pkh(s[0][in_][2], s[0][in_][3]);
            int w10 = (int)pkh(s[1][in_][0], s[1][in_][1]);
            int w11 = (int)pkh(s[1][in_][2], s[1][in_][3]);

            int a0 = __shfl(w00, idx0, 64), a1 = __shfl(w01, idx0, 64);
            int a2 = __shfl(w00, idx1, 64), a3 = __shfl(w01, idx1, 64);
            int b0 = __shfl(w10, idx0, 64), b1 = __shfl(w11, idx0, 64);
            int b2 = __shfl(w10, idx1, 64), b3 = __shfl(w11, idx1, 64);
            F8U fu;
            fu.u[0] = (uint32_t)(topTile ? b0 : a0);
            fu.u[1] = (uint32_t)(topTile ? b1 : a1);
            fu.u[2] = (uint32_t)(topTile ? b2 : a2);
            fu.u[3] = (uint32_t)(topTile ? b3 : a3);

            __builtin_amdgcn_s_setprio(1);
            #pragma unroll
            for (int cm = 0; cm < 4; ++cm)
                acc[cm][in_] = MFMA16(vf[cm], fu.v, acc[cm][in_]);
            __builtin_amdgcn_s_setprio(0);
        }

        __syncthreads();
    }

    #pragma unroll
    for (int in_ = 0; in_ < NIN; ++in_) {
        float inv = 1.0f / lst[in_];
        int i = i0 + 16 * in_ + ln;
        #pragma unroll
        for (int cm = 0; cm < 4; ++cm) {
            f32x4 o4 = acc[cm][in_] * inv;
            uint32_t h01, h23, l01, l23;
            split2(o4[0], o4[1], h01, l01);
            split2(o4[2], o4[3], h23, l23);
            u32x4 wv; wv[0] = h01; wv[1] = h23; wv[2] = l01; wv[3] = l23;
            size_t idx = ((size_t)b * P + i) * 512 + (size_t)(h * DH + 16 * cm + 4 * g);
            *reinterpret_cast<u32x4*>(ohl + idx) = wv;
        }
    }
}

// ---------------------------------------------------------------------------
// Output projection (unchanged from R9): out = Wo @ O + bo, 2-term fp16 MFMA.
// ---------------------------------------------------------------------------
__global__ __launch_bounds__(256, 4) void out_proj(
    const unsigned short* __restrict__ woh, const uint32_t* __restrict__ ohl,
    const float* __restrict__ bo, float* __restrict__ out)
{
    const int wid = threadIdx.x >> 6;
    const int l = threadIdx.x & 63;
    const int ln = l & 15, g = l >> 4;
    const int ibase = blockIdx.x * 128 + wid * 32;
    const int otile = blockIdx.y * 32;
    const int b = blockIdx.z;

    f32x4 acc[2][2];
    #pragma unroll
    for (int mt = 0; mt < 2; ++mt)
        #pragma unroll
        for (int nt = 0; nt < 2; ++nt) {
            f32x4 z = {0.f, 0.f, 0.f, 0.f};
            acc[mt][nt] = z;
        }

    #pragma unroll
    for (int ks = 0; ks < 16; ++ks) {
        const int c0 = 32 * ks + 8 * g;
        f16x8 wf[2];
        #pragma unroll
        for (int mt = 0; mt < 2; ++mt)
            wf[mt] = *reinterpret_cast<const f16x8*>(
                woh + (size_t)(otile + 16 * mt + ln) * HID + c0);
        #pragma unroll
        for (int nt = 0; nt < 2; ++nt) {
            const size_t obase = ((size_t)b * P + ibase + 16 * nt + ln) * 512 + c0;
            u32x4 A = *reinterpret_cast<const u32x4*>(ohl + obase);
            u32x4 Bv = *reinterpret_cast<const u32x4*>(ohl + obase + 4);
            F8U bh, bl;
            bh.u[0] = A[0]; bh.u[1] = A[1]; bh.u[2] = Bv[0]; bh.u[3] = Bv[1];
            bl.u[0] = A[2]; bl.u[1] = A[3]; bl.u[2] = Bv[2]; bl.u[3] = Bv[3];
            #pragma unroll
            for (int mt = 0; mt < 2; ++mt) {
                acc[mt][nt] = MFMA16(wf[mt], bh.v, acc[mt][nt]);
                acc[mt][nt] = MFMA16(wf[mt], bl.v, acc[mt][nt]);
            }
        }
    }

    #pragma unroll
    for (int mt = 0; mt < 2; ++mt)
        #pragma unroll
        for (int r = 0; r < 4; ++r) {
            int o_ = otile + 16 * mt + 4 * g + r;
            float bv = bo[o_];
            #pragma unroll
            for (int nt = 0; nt < 2; ++nt)
                out[((size_t)b * CQ + o_) * P + ibase + 16 * nt + ln] =
                    acc[mt][nt][r] + bv;
        }
}

extern "C" void kernel_launch(void* const* d_in, const int* in_sizes, int n_in,
                              void* d_out, int out_size, void* d_ws, size_t ws_size,
                              hipStream_t stream) {
    (void)in_sizes; (void)n_in; (void)out_size; (void)ws_size;
    const float* x   = (const float*)d_in[0];
    const float* ctx = (const float*)d_in[1];
    const float* Wq  = (const float*)d_in[2];
    const float* Wk  = (const float*)d_in[3];
    const float* Wv  = (const float*)d_in[4];
    const float* Wo  = (const float*)d_in[5];
    const float* bo  = (const float*)d_in[6];
    float* out = (float*)d_out;

    // Workspace layout (ushort units). ohl [0, 16777216) aliases the
    // transposed input splits (xh/xl/ctxh/ctxl), which are dead before
    // attn writes ohl (stream-sequential).
    unsigned short* ws = (unsigned short*)d_ws;
    uint32_t* ohl        = (uint32_t*)ws;            // 8388608 u32 = 33.5 MB
    unsigned short* xh   = ws;                       // 4194304
    unsigned short* xl   = ws + (size_t)4194304;
    unsigned short* ctxh = ws + (size_t)8388608;     // 2097152
    unsigned short* ctxl = ws + (size_t)10485760;
    unsigned short* qh   = ws + (size_t)16777216;    // 8388608
    unsigned short* ql   = qh + (size_t)8388608;
    unsigned short* kh   = ql + (size_t)8388608;     // 2097152
    unsigned short* kl   = kh + (size_t)2097152;
    unsigned short* vh   = kl + (size_t)2097152;     // 2097152
    unsigned short* woh  = vh + (size_t)2097152;     // 131072
    unsigned short* wqh  = woh + (size_t)131072;     // 131072
    unsigned short* wql  = wqh + (size_t)131072;
    unsigned short* wkh  = wql + (size_t)131072;     // 262144
    unsigned short* wkl  = wkh + (size_t)262144;
    unsigned short* wvh  = wkl + (size_t)262144;
    unsigned short* wvl  = wvh + (size_t)262144;

    dim3 blk(256);
    // 1. weight splits
    split_all<<<dim3(3072), blk, 0, stream>>>(
        Wq, Wk, Wv, Wo, wqh, wql, wkh, wkl, wvh, wvl, woh);
    // 2. input transpose-splits
    split_tr<<<dim3(P / 64, CQ / 64, BATCH), blk, 0, stream>>>(x, xh, xl, CQ, P);
    split_tr<<<dim3(PC / 64, CC / 64, BATCH), blk, 0, stream>>>(ctx, ctxh, ctxl, CC, PC);
    // 3. projections (MFMA)
    proj_q<<<dim3(P / 64, HID / 128, BATCH), blk, 0, stream>>>(
        wqh, wql, xh, xl, qh, ql);
    proj_kv<<<dim3(PC / 64, 8, BATCH), blk, 0, stream>>>(
        wkh, wkl, wvh, wvl, ctxh, ctxl, kh, kl, vh);
    // 4. attention -> ohl (clobbers xh/xl/ctxh/ctxl — dead by now)
    attn_mfma<<<dim3(HEADS * BATCH, P / 256), blk, 0, stream>>>(
        qh, ql, kh, kl, vh, ohl);
    // 5. out = Wo @ O + bo
    out_proj<<<dim3(P / 128, CQ / 32, BATCH), blk, 0, stream>>>(
        woh, ohl, bo, out);
}